// Round 1
// baseline (1200.613 us; speedup 1.0000x reference)
//
#include <hip/hip_runtime.h>
#include <stdint.h>
#include <math.h>

#define NH    12
#define SEQ   2048
#define BATCH 2
#define DM    768
#define HD    64
#define QT    8            // queries per workgroup in attention
#define SCALEF 0.125f      // 1/sqrt(64)

typedef unsigned short u16;
typedef unsigned int   u32;
typedef unsigned long long u64;
typedef __attribute__((ext_vector_type(8))) short bf16x8;
typedef __attribute__((ext_vector_type(4))) float f32x4;

__device__ __forceinline__ u16 f2bf(float f){
  u32 u = __float_as_uint(f);
  u32 r = u + 0x7fffu + ((u >> 16) & 1u);
  return (u16)(r >> 16);
}
__device__ __forceinline__ float bf2f(u16 x){ return __uint_as_float(((u32)x) << 16); }

__device__ __forceinline__ float wred_max(float x){
  #pragma unroll
  for (int m = 32; m; m >>= 1) x = fmaxf(x, __shfl_xor(x, m));
  return x;
}
__device__ __forceinline__ float wred_sum(float x){
  #pragma unroll
  for (int m = 32; m; m >>= 1) x += __shfl_xor(x, m);
  return x;
}
__device__ __forceinline__ int wred_sumi(int x){
  #pragma unroll
  for (int m = 32; m; m >>= 1) x += __shfl_xor(x, m);
  return x;
}
__device__ __forceinline__ int wprefix_excl(int x){
  int v = x;
  int lane = threadIdx.x & 63;
  #pragma unroll
  for (int off = 1; off < 64; off <<= 1){
    int y = __shfl_up(v, off);
    if (lane >= off) v += y;
  }
  return v - x;
}

// ---------------------------------------------------------------- cvt fp32->bf16
__global__ void cvt_kernel(const float* s0, const float* s1, const float* s2, const float* s3,
                           u16* d0, u16* d1, u16* d2, u16* d3, int n){
  const float* s; u16* d;
  switch (blockIdx.y){
    case 0: s = s0; d = d0; break;
    case 1: s = s1; d = d1; break;
    case 2: s = s2; d = d2; break;
    default: s = s3; d = d3; break;
  }
  int i = (blockIdx.x * 256 + threadIdx.x) * 4;
  if (i < n){
    float4 v = *(const float4*)(s + i);
    ushort4 o;
    o.x = f2bf(v.x); o.y = f2bf(v.y); o.z = f2bf(v.z); o.w = f2bf(v.w);
    *(ushort4*)(d + i) = o;
  }
}

// ---------------------------------------------------------------- GEMM  C = A @ W^T (+bias)
// A: [4096][768] bf16 row-major (K contiguous), W: [768][768] bf16 row-major (K contiguous).
// MODE 0: out bf16 head-split layout [(b*NH+h)*SEQ + s]*HD + d, z = {q,k,v}
// MODE 1: out fp32 plain [m][n] (final output projection)
template<int MODE>
__global__ __launch_bounds__(256) void gemm_bt(const u16* __restrict__ Aall, const u16* __restrict__ Wall,
      const float* __restrict__ bz0, const float* __restrict__ bz1, const float* __restrict__ bz2,
      u16* __restrict__ outb, float* __restrict__ outf){
  __shared__ u16 As[128][40];   // pad 32->40 to break LDS bank alignment
  __shared__ u16 Bs[128][40];
  const int zz = blockIdx.z;
  const u16* A = Aall + (size_t)zz * 4096 * 768;
  const u16* W = Wall + (size_t)zz * 768 * 768;
  const float* bias = (zz == 0) ? bz0 : (zz == 1 ? bz1 : bz2);
  const int m0 = blockIdx.x * 128, n0 = blockIdx.y * 128;
  const int t = threadIdx.x, lane = t & 63, wv = t >> 6;
  const int wm = wv >> 1, wn = wv & 1;          // 2x2 wave grid, 64x64 per wave
  f32x4 acc[4][4] = {};
  const int arow = t >> 1, aseg = t & 1;
  const u16* ap = A + (size_t)(m0 + arow) * 768 + aseg * 16;
  const u16* bp = W + (size_t)(n0 + arow) * 768 + aseg * 16;
  for (int kt = 0; kt < 768; kt += 32){
    uint4 av0 = *(const uint4*)(ap + kt);
    uint4 av1 = *(const uint4*)(ap + kt + 8);
    uint4 bv0 = *(const uint4*)(bp + kt);
    uint4 bv1 = *(const uint4*)(bp + kt + 8);
    __syncthreads();
    *(uint4*)&As[arow][aseg*16]     = av0;
    *(uint4*)&As[arow][aseg*16 + 8] = av1;
    *(uint4*)&Bs[arow][aseg*16]     = bv0;
    *(uint4*)&Bs[arow][aseg*16 + 8] = bv1;
    __syncthreads();
    bf16x8 af[4], bq[4];
    #pragma unroll
    for (int i = 0; i < 4; ++i) af[i] = *(const bf16x8*)&As[wm*64 + i*16 + (lane & 15)][(lane >> 4) * 8];
    #pragma unroll
    for (int i = 0; i < 4; ++i) bq[i] = *(const bf16x8*)&Bs[wn*64 + i*16 + (lane & 15)][(lane >> 4) * 8];
    #pragma unroll
    for (int mi = 0; mi < 4; ++mi)
      #pragma unroll
      for (int ni = 0; ni < 4; ++ni)
        acc[mi][ni] = __builtin_amdgcn_mfma_f32_16x16x32_bf16(af[mi], bq[ni], acc[mi][ni], 0, 0, 0);
  }
  #pragma unroll
  for (int mi = 0; mi < 4; ++mi){
    #pragma unroll
    for (int ni = 0; ni < 4; ++ni){
      const int n = n0 + wn*64 + ni*16 + (lane & 15);
      const float bval = bias[n];
      #pragma unroll
      for (int r = 0; r < 4; ++r){
        const int m = m0 + wm*64 + mi*16 + (lane >> 4) * 4 + r;
        const float v = acc[mi][ni][r] + bval;
        if (MODE == 0){
          const int bb = m >> 11, ss = m & 2047, hh = n >> 6, dd = n & 63;
          outb[(size_t)zz * 3145728 + (((size_t)bb * NH + hh) * SEQ + ss) * HD + dd] = f2bf(v);
        } else {
          outf[(size_t)m * DM + n] = v;
        }
      }
    }
  }
}

// ---------------------------------------------------------------- fused attention
// grid (SEQ/QT, NH, BATCH), 256 threads (4 waves). Per WG: 8 queries of one (b,h).
__global__ __launch_bounds__(256) void attn_kernel(const u16* __restrict__ Qh, const u16* __restrict__ Kh,
      const u16* __restrict__ Vh, u16* __restrict__ ctxb){
  __shared__ float sc[QT * SEQ];        // 64 KB score stripe
  __shared__ u16  kbuf[64 * 64];        // 8 KB K chunk (XOR-swizzled 16B blocks)
  __shared__ float s_val[4 * 64];
  __shared__ u32  s_idx[4 * 64];

  const int q0 = blockIdx.x * QT;
  const int h = blockIdx.y, b = blockIdx.z;
  const int bh = b * NH + h;
  const int t = threadIdx.x, lane = t & 63, wv = t >> 6;
  const u16* Qb = Qh + ((size_t)bh * SEQ + q0) * HD;
  const u16* Kb = Kh + (size_t)bh * SEQ * HD;
  const u16* Vb = Vh + (size_t)bh * SEQ * HD;

  // Q fragments (A operand): row = lane&15 (clamped to QT-1), k = (lane>>4)*8 (+32)
  const int qr = (lane & 15) < QT ? (lane & 15) : (QT - 1);
  const bf16x8 a0 = *(const bf16x8*)(Qb + qr * HD + (lane >> 4) * 8);
  const bf16x8 a1 = *(const bf16x8*)(Qb + qr * HD + 32 + (lane >> 4) * 8);

  // ---- phase 1: scores stripe via MFMA, 64-key chunks
  for (int ch = 0; ch < SEQ / 64; ++ch){
    __syncthreads();                    // previous chunk's reads done
    #pragma unroll
    for (int j = 0; j < 2; ++j){        // stage 64x64 bf16, swizzle: sub ^= row&7 (16B units)
      const int g = t * 2 + j;          // 0..511
      const int row = g >> 3, sub = g & 7;
      const uint4 x = *(const uint4*)(Kb + (size_t)(ch * 64 + row) * HD + (sub ^ (row & 7)) * 8);
      *(uint4*)(kbuf + row * 64 + sub * 8) = x;
    }
    __syncthreads();
    const int kl = wv * 16 + (lane & 15);      // local key this lane provides (B col)
    const int sw = kl & 7;
    const bf16x8 bf0 = *(const bf16x8*)(kbuf + kl * 64 + (((lane >> 4)    ) ^ sw) * 8);
    const bf16x8 bf1 = *(const bf16x8*)(kbuf + kl * 64 + (((lane >> 4) + 4) ^ sw) * 8);
    f32x4 d = {};
    d = __builtin_amdgcn_mfma_f32_16x16x32_bf16(a0, bf0, d, 0, 0, 0);
    d = __builtin_amdgcn_mfma_f32_16x16x32_bf16(a1, bf1, d, 0, 0, 0);
    const int col = ch * 64 + kl;
    #pragma unroll
    for (int r = 0; r < 4; ++r){
      const int qq = (lane >> 4) * 4 + r;
      if (qq < QT) sc[qq * SEQ + col] = d[r] * SCALEF;
    }
  }
  __syncthreads();

  // ---- phases 2-4: per-wave, 2 query rows each
  float* svals = s_val + wv * 64;
  u32*  sidx   = s_idx + wv * 64;
  #pragma unroll 1
  for (int rep = 0; rep < 2; ++rep){
    const int qq = wv * 2 + rep;
    const int qi = q0 + qq;
    float* row = sc + qq * SEQ;

    // row -> regs (strided: lane + 64*i, conflict-free)
    float v[32]; u32 u[32];
    #pragma unroll
    for (int i = 0; i < 32; ++i) v[i] = row[lane + 64 * i];
    #pragma unroll
    for (int i = 0; i < 32; ++i){
      u32 x = __float_as_uint(v[i]);
      u[i] = (x & 0x80000000u) ? ~x : (x | 0x80000000u);   // order-preserving map
    }

    // binary search for 64th-largest bit pattern
    u32 tval = 0; bool done = false;
    for (int bit = 31; bit >= 0 && !done; --bit){
      const u32 cand = tval | (1u << bit);
      int c = 0;
      #pragma unroll
      for (int i = 0; i < 32; ++i) c += (u[i] >= cand) ? 1 : 0;
      c = wred_sumi(c);
      if (c >= 64){ tval = cand; if (c == 64) done = true; }
    }
    int ngt = 0;
    #pragma unroll
    for (int i = 0; i < 32; ++i) ngt += (u[i] > tval) ? 1 : 0;
    const int G = wred_sumi(ngt);
    const int r_need = 64 - G;
    const int pre = wprefix_excl(ngt);
    int k2 = 0;
    #pragma unroll
    for (int i = 0; i < 32; ++i){
      if (u[i] > tval){ svals[pre + k2] = v[i]; sidx[pre + k2] = lane + 64 * i; ++k2; }
    }
    // tie fill: lowest global index first (matches lax.top_k)
    int filled = 0;
    for (int i = 0; i < 32 && filled < r_need; ++i){
      const bool eq = (u[i] == tval);
      const u64 bal = __ballot(eq);
      const int myrank = filled + (int)__popcll(bal & ((1ull << lane) - 1ull));
      if (eq && myrank < r_need){ svals[G + myrank] = v[i]; sidx[G + myrank] = lane + 64 * i; }
      filled += (int)__popcll(bal);
    }
    __asm__ volatile("" ::: "memory");

    // sparse softmax over exactly 64 entries (x0.5 combine factor folded in)
    const float svv = svals[lane];
    const float m1 = wred_max(svv);
    const float e1 = __expf(svv - m1);
    const float Z1 = wred_sum(e1);
    svals[lane] = e1 * (0.5f / Z1);
    __asm__ volatile("" ::: "memory");

    // sparse PV gather: lane = head dim
    float acc = 0.f;
    #pragma unroll 8
    for (int tt = 0; tt < 64; ++tt){
      acc += svals[tt] * bf2f(Vb[(size_t)sidx[tt] * HD + lane]);
    }

    // windowed causal branch: j in [max(0,qi-256), qi]
    const int start = (qi - 256 > 0) ? (qi - 256) : 0;
    float wvv[5]; float wm = -INFINITY;
    #pragma unroll
    for (int it = 0; it < 5; ++it){
      const int c = start + lane + it * 64;
      const float x = (c <= qi) ? row[c] : -INFINITY;
      wvv[it] = x; wm = fmaxf(wm, x);
    }
    wm = wred_max(wm);
    float zs = 0.f;
    #pragma unroll
    for (int it = 0; it < 5; ++it){
      const int c = start + lane + it * 64;
      if (c <= qi){ const float e = __expf(wvv[it] - wm); wvv[it] = e; zs += e; }
    }
    zs = wred_sum(zs);
    const float inv = 0.5f / zs;
    #pragma unroll
    for (int it = 0; it < 5; ++it){
      const int c = start + lane + it * 64;
      if (c <= qi) row[c] = wvv[it] * inv;     // overwrite scores with probs (row is wave-private)
    }
    __asm__ volatile("" ::: "memory");
    for (int j = start; j <= qi; ++j){
      acc += row[j] * bf2f(Vb[(size_t)j * HD + lane]);   // row[j] is a broadcast LDS read
    }

    ctxb[((size_t)b * SEQ + qi) * DM + h * HD + lane] = f2bf(acc);
  }
}

// ---------------------------------------------------------------- host
extern "C" void kernel_launch(void* const* d_in, const int* in_sizes, int n_in,
                              void* d_out, int out_size, void* d_ws, size_t ws_size,
                              hipStream_t stream){
  const float* q_in = (const float*)d_in[0];
  const float* k_in = (const float*)d_in[1];
  const float* v_in = (const float*)d_in[2];
  const float* Wq = (const float*)d_in[3];
  const float* bq = (const float*)d_in[4];
  const float* Wk = (const float*)d_in[5];
  const float* bk = (const float*)d_in[6];
  const float* Wv = (const float*)d_in[7];
  const float* bv = (const float*)d_in[8];
  const float* Wo = (const float*)d_in[9];
  const float* bo = (const float*)d_in[10];

  char* ws = (char*)d_ws;
  u16* Xb   = (u16*)ws;                                   // 3 x 4096x768 bf16   (18,874,368 B)
  u16* Wb   = (u16*)(ws + 18874368);                      // 4 x 768x768 bf16    ( 4,718,592 B)
  u16* QKVh = (u16*)(ws + 23592960);                      // 3 x [B,H,S,64] bf16 (18,874,368 B)
  u16* ctxb = (u16*)(ws + 42467328);                      // 4096x768 bf16       ( 6,291,456 B)

  // 1) convert inputs + weights to bf16
  cvt_kernel<<<dim3(3145728 / 1024, 3), 256, 0, stream>>>(
      q_in, k_in, v_in, nullptr, Xb, Xb + 3145728, Xb + 2 * 3145728, nullptr, 3145728);
  cvt_kernel<<<dim3(589824 / 1024, 4), 256, 0, stream>>>(
      Wq, Wk, Wv, Wo, Wb, Wb + 589824, Wb + 2 * 589824, Wb + 3 * 589824, 589824);

  // 2) QKV projections (z = q/k/v) -> head-split bf16
  gemm_bt<0><<<dim3(32, 6, 3), 256, 0, stream>>>(Xb, Wb, bq, bk, bv, QKVh, nullptr);

  // 3) fused dual-branch attention -> ctx bf16 [4096][768]
  attn_kernel<<<dim3(SEQ / QT, NH, BATCH), 256, 0, stream>>>(
      QKVh, QKVh + 3145728, QKVh + 2 * 3145728, ctxb);

  // 4) output projection -> fp32 d_out
  gemm_bt<1><<<dim3(32, 6, 1), 256, 0, stream>>>(
      ctxb, Wb + 3 * 589824, bo, bo, bo, nullptr, (float*)d_out);
}

// Round 2
// 661.624 us; speedup vs baseline: 1.8146x; 1.8146x over previous
//
#include <hip/hip_runtime.h>
#include <hip/hip_fp16.h>
#include <stdint.h>
#include <math.h>

#define NH    12
#define SEQ   2048
#define BATCH 2
#define DM    768
#define HD    64
#define SCALEF 0.125f      // 1/sqrt(64)

typedef unsigned short u16;
typedef unsigned int   u32;
typedef unsigned long long u64;
typedef __attribute__((ext_vector_type(8))) short bf16x8;
typedef __attribute__((ext_vector_type(8))) _Float16 h16x8;
typedef __attribute__((ext_vector_type(4))) float f32x4;

__device__ __forceinline__ u16 f2bf(float f){
  u32 u = __float_as_uint(f);
  u32 r = u + 0x7fffu + ((u >> 16) & 1u);
  return (u16)(r >> 16);
}
__device__ __forceinline__ float bf2f(u16 x){ return __uint_as_float(((u32)x) << 16); }
__device__ __forceinline__ u16 f2h(float f){ return __half_as_ushort(__float2half(f)); }
__device__ __forceinline__ float h2f(u16 x){ return __half2float(__ushort_as_half(x)); }

__device__ __forceinline__ float wred_max(float x){
  #pragma unroll
  for (int m = 32; m; m >>= 1) x = fmaxf(x, __shfl_xor(x, m));
  return x;
}
__device__ __forceinline__ float wred_sum(float x){
  #pragma unroll
  for (int m = 32; m; m >>= 1) x += __shfl_xor(x, m);
  return x;
}
__device__ __forceinline__ int wred_sumi(int x){
  #pragma unroll
  for (int m = 32; m; m >>= 1) x += __shfl_xor(x, m);
  return x;
}
__device__ __forceinline__ int wprefix_excl(int x){
  int v = x;
  int lane = threadIdx.x & 63;
  #pragma unroll
  for (int off = 1; off < 64; off <<= 1){
    int y = __shfl_up(v, off);
    if (lane >= off) v += y;
  }
  return v - x;
}

// swizzled fp32 score stripe sc[8][2048]: 16B-block XOR by row -> conflict-free col access
__device__ __forceinline__ int sc_off(int row, int k){
  return (row << 11) + ((((k >> 2) ^ (row & 7)) << 2) | (k & 3));
}
// swizzled fp16 prob matrix Pb[16][2048]
__device__ __forceinline__ int pb_off(int q, int k){
  return (q << 11) + ((((k >> 3) ^ (q & 7)) << 3) | (k & 7));
}

// ---------------------------------------------------------------- cvt fp32->bf16
__global__ void cvt_kernel(const float* s0, const float* s1, const float* s2, const float* s3,
                           u16* d0, u16* d1, u16* d2, u16* d3, int n){
  const float* s; u16* d;
  switch (blockIdx.y){
    case 0: s = s0; d = d0; break;
    case 1: s = s1; d = d1; break;
    case 2: s = s2; d = d2; break;
    default: s = s3; d = d3; break;
  }
  int i = (blockIdx.x * 256 + threadIdx.x) * 4;
  if (i < n){
    float4 v = *(const float4*)(s + i);
    ushort4 o;
    o.x = f2bf(v.x); o.y = f2bf(v.y); o.z = f2bf(v.z); o.w = f2bf(v.w);
    *(ushort4*)(d + i) = o;
  }
}

// ---------------------------------------------------------------- GEMM  C = A @ W^T (+bias)
// MODE 0: zz=0,1 -> bf16 head-split [(b*NH+h)*SEQ+s]*HD+d ; zz=2 -> fp16 V^T [(b*NH+h)*HD+d]*SEQ+s
// MODE 1: out fp32 plain [m][n]
template<int MODE>
__global__ __launch_bounds__(256) void gemm_bt(const u16* __restrict__ Aall, const u16* __restrict__ Wall,
      const float* __restrict__ bz0, const float* __restrict__ bz1, const float* __restrict__ bz2,
      u16* __restrict__ outb, float* __restrict__ outf){
  __shared__ u16 As[128][40];
  __shared__ u16 Bs[128][40];
  const int zz = blockIdx.z;
  const u16* A = Aall + (size_t)zz * 4096 * 768;
  const u16* W = Wall + (size_t)zz * 768 * 768;
  const float* bias = (zz == 0) ? bz0 : (zz == 1 ? bz1 : bz2);
  const int m0 = blockIdx.x * 128, n0 = blockIdx.y * 128;
  const int t = threadIdx.x, lane = t & 63, wv = t >> 6;
  const int wm = wv >> 1, wn = wv & 1;
  f32x4 acc[4][4] = {};
  const int arow = t >> 1, aseg = t & 1;
  const u16* ap = A + (size_t)(m0 + arow) * 768 + aseg * 16;
  const u16* bp = W + (size_t)(n0 + arow) * 768 + aseg * 16;
  for (int kt = 0; kt < 768; kt += 32){
    uint4 av0 = *(const uint4*)(ap + kt);
    uint4 av1 = *(const uint4*)(ap + kt + 8);
    uint4 bv0 = *(const uint4*)(bp + kt);
    uint4 bv1 = *(const uint4*)(bp + kt + 8);
    __syncthreads();
    *(uint4*)&As[arow][aseg*16]     = av0;
    *(uint4*)&As[arow][aseg*16 + 8] = av1;
    *(uint4*)&Bs[arow][aseg*16]     = bv0;
    *(uint4*)&Bs[arow][aseg*16 + 8] = bv1;
    __syncthreads();
    bf16x8 af[4], bq[4];
    #pragma unroll
    for (int i = 0; i < 4; ++i) af[i] = *(const bf16x8*)&As[wm*64 + i*16 + (lane & 15)][(lane >> 4) * 8];
    #pragma unroll
    for (int i = 0; i < 4; ++i) bq[i] = *(const bf16x8*)&Bs[wn*64 + i*16 + (lane & 15)][(lane >> 4) * 8];
    #pragma unroll
    for (int mi = 0; mi < 4; ++mi)
      #pragma unroll
      for (int ni = 0; ni < 4; ++ni)
        acc[mi][ni] = __builtin_amdgcn_mfma_f32_16x16x32_bf16(af[mi], bq[ni], acc[mi][ni], 0, 0, 0);
  }
  #pragma unroll
  for (int mi = 0; mi < 4; ++mi){
    #pragma unroll
    for (int ni = 0; ni < 4; ++ni){
      const int n = n0 + wn*64 + ni*16 + (lane & 15);
      const float bval = bias[n];
      const int mbase = m0 + wm*64 + mi*16 + (lane >> 4) * 4;
      if (MODE == 0 && zz == 2){
        const int bb = mbase >> 11, ss = mbase & 2047;
        const int hh = n >> 6, dd = n & 63;
        u64 pk = 0;
        #pragma unroll
        for (int r = 0; r < 4; ++r) pk |= (u64)f2h(acc[mi][ni][r] + bval) << (16 * r);
        *(u64*)(outb + (size_t)2 * 3145728 + (((size_t)(bb * NH + hh) * HD + dd) * SEQ + ss)) = pk;
      } else if (MODE == 0){
        #pragma unroll
        for (int r = 0; r < 4; ++r){
          const int m = mbase + r;
          const int bb = m >> 11, ss = m & 2047, hh = n >> 6, dd = n & 63;
          outb[(size_t)zz * 3145728 + (((size_t)bb * NH + hh) * SEQ + ss) * HD + dd] = f2bf(acc[mi][ni][r] + bval);
        }
      } else {
        #pragma unroll
        for (int r = 0; r < 4; ++r){
          const int m = mbase + r;
          outf[(size_t)m * DM + n] = acc[mi][ni][r] + bval;
        }
      }
    }
  }
}

// ---------------------------------------------------------------- fused attention v2
// grid (SEQ/16, NH, BATCH), 512 threads (8 waves), 16 queries per WG.
__global__ __launch_bounds__(512, 2) void attn2_kernel(const u16* __restrict__ Qh,
      const u16* __restrict__ Kh, const u16* __restrict__ Vt, u16* __restrict__ ctxb){
  __shared__ __align__(16) float sc[8 * SEQ];    // 64 KB fp32 scores (one 8-query round)
  __shared__ __align__(16) u16  Pb[16 * SEQ];    // 64 KB fp16 combined probs
  __shared__ float s_val[8 * 64];
  __shared__ u32  s_idx[8 * 64];

  const int q0 = blockIdx.x * 16;
  const int h = blockIdx.y, b = blockIdx.z, bh = b * NH + h;
  const int t = threadIdx.x, lane = t & 63, w = t >> 6;
  const u16* Qb  = Qh + ((size_t)bh * SEQ + q0) * HD;
  const u16* Kb  = Kh + (size_t)bh * SEQ * HD;
  const u16* Vtb = Vt + (size_t)bh * HD * SEQ;

  // zero P matrix (64 KB)
  const uint4 z4 = {0u, 0u, 0u, 0u};
  #pragma unroll
  for (int i = 0; i < 8; ++i) ((uint4*)Pb)[i * 512 + t] = z4;

  float* svals = s_val + w * 64;
  u32*  sidx   = s_idx + w * 64;

  #pragma unroll 1
  for (int rnd = 0; rnd < 2; ++rnd){
    // ---- QK^T: A = K-tile, B = Q^T (8 real query cols). wave w covers keys [w*256, w*256+256)
    const int qsel = rnd * 8 + ((lane & 15) & 7);
    const bf16x8 qa0 = *(const bf16x8*)(Qb + qsel * HD + (lane >> 4) * 8);
    const bf16x8 qa1 = *(const bf16x8*)(Qb + qsel * HD + 32 + (lane >> 4) * 8);
    #pragma unroll 4
    for (int tile = 0; tile < 16; ++tile){
      const int kr = w * 256 + tile * 16 + (lane & 15);
      const bf16x8 ka0 = *(const bf16x8*)(Kb + (size_t)kr * HD + (lane >> 4) * 8);
      const bf16x8 ka1 = *(const bf16x8*)(Kb + (size_t)kr * HD + 32 + (lane >> 4) * 8);
      f32x4 d = {};
      d = __builtin_amdgcn_mfma_f32_16x16x32_bf16(ka0, qa0, d, 0, 0, 0);
      d = __builtin_amdgcn_mfma_f32_16x16x32_bf16(ka1, qa1, d, 0, 0, 0);
      if ((lane & 15) < 8){
        const int kcol = w * 256 + tile * 16 + (lane >> 4) * 4;
        *(f32x4*)&sc[sc_off(lane & 15, kcol)] = d * SCALEF;
      }
    }
    __syncthreads();

    // ---- selection + softmax: wave w owns query qq = rnd*8 + w
    const int qq = rnd * 8 + w;
    const int qi = q0 + qq;

    float v[32]; u32 u[32];
    #pragma unroll
    for (int i = 0; i < 32; ++i) v[i] = sc[sc_off(w, lane + 64 * i)];
    #pragma unroll
    for (int i = 0; i < 32; ++i){
      u32 x = __float_as_uint(v[i]);
      u[i] = (x & 0x80000000u) ? ~x : (x | 0x80000000u);
    }

    // binary search for 64th-largest bit pattern
    u32 tval = 0; bool done = false;
    for (int bit = 31; bit >= 0 && !done; --bit){
      const u32 cand = tval | (1u << bit);
      int c = 0;
      #pragma unroll
      for (int i = 0; i < 32; ++i) c += (u[i] >= cand) ? 1 : 0;
      c = wred_sumi(c);
      if (c >= 64){ tval = cand; if (c == 64) done = true; }
    }
    int ngt = 0;
    #pragma unroll
    for (int i = 0; i < 32; ++i) ngt += (u[i] > tval) ? 1 : 0;
    const int G = wred_sumi(ngt);
    const int r_need = 64 - G;
    const int pre = wprefix_excl(ngt);
    int k2 = 0;
    #pragma unroll
    for (int i = 0; i < 32; ++i){
      if (u[i] > tval){ svals[pre + k2] = v[i]; sidx[pre + k2] = lane + 64 * i; ++k2; }
    }
    int filled = 0;
    for (int i = 0; i < 32 && filled < r_need; ++i){
      const bool eq = (u[i] == tval);
      const u64 bal = __ballot(eq);
      const int myrank = filled + (int)__popcll(bal & ((1ull << lane) - 1ull));
      if (eq && myrank < r_need){ svals[G + myrank] = v[i]; sidx[G + myrank] = lane + 64 * i; }
      filled += (int)__popcll(bal);
    }
    __asm__ volatile("" ::: "memory");

    // sparse softmax over exactly 64 entries (x0.5 folded)
    const float svv = svals[lane];
    const float m1 = wred_max(svv);
    const float e1 = __expf(svv - m1);
    const float Z1 = wred_sum(e1);
    const float padd = e1 * (0.5f / Z1);
    const int  ksp  = (int)sidx[lane];

    // windowed causal branch: j in [max(0,qi-256), qi]
    const int start = (qi - 256 > 0) ? (qi - 256) : 0;
    float wvv[5]; float wm = -INFINITY;
    #pragma unroll
    for (int it = 0; it < 5; ++it){
      const int c = start + lane + it * 64;
      const float x = (c <= qi) ? sc[sc_off(w, c)] : -INFINITY;
      wvv[it] = x; wm = fmaxf(wm, x);
    }
    wm = wred_max(wm);
    float zs = 0.f;
    #pragma unroll
    for (int it = 0; it < 5; ++it){
      const int c = start + lane + it * 64;
      if (c <= qi){ const float e = __expf(wvv[it] - wm); wvv[it] = e; zs += e; }
    }
    zs = wred_sum(zs);
    const float inv = 0.5f / zs;
    #pragma unroll
    for (int it = 0; it < 5; ++it){
      const int c = start + lane + it * 64;
      if (c <= qi) Pb[pb_off(qq, c)] = f2h(wvv[it] * inv);
    }
    __asm__ volatile("s_waitcnt lgkmcnt(0)" ::: "memory");
    // sparse add (window/topk overlap accumulates); distinct ksp per lane
    {
      u16* cell = &Pb[pb_off(qq, ksp)];
      *cell = f2h(h2f(*cell) + padd);
    }
    __syncthreads();
  }

  // ---- PV: out^T[d][q] = V^T · P^T  (fp16 MFMA). wave w: mtile = w&3, k-half = w>>2
  const int mt = w & 3, kh = w >> 2;
  f32x4 acc = {};
  #pragma unroll 8
  for (int ks = kh * 32; ks < kh * 32 + 32; ++ks){
    const h16x8 va = *(const h16x8*)(Vtb + (size_t)(mt * 16 + (lane & 15)) * SEQ + ks * 32 + (lane >> 4) * 8);
    const h16x8 pbf = *(const h16x8*)&Pb[pb_off(lane & 15, ks * 32 + (lane >> 4) * 8)];
    acc = __builtin_amdgcn_mfma_f32_16x16x32_f16(va, pbf, acc, 0, 0, 0);
  }
  float4* psum = (float4*)sc;
  float4 mine; mine.x = acc[0]; mine.y = acc[1]; mine.z = acc[2]; mine.w = acc[3];
  psum[w * 64 + lane] = mine;
  __syncthreads();
  if (w < 4){
    const float4 x = psum[w * 64 + lane];
    const float4 y = psum[(w + 4) * 64 + lane];
    const float r0 = x.x + y.x, r1 = x.y + y.y, r2 = x.z + y.z, r3 = x.w + y.w;
    u64 pk = (u64)f2bf(r0) | ((u64)f2bf(r1) << 16) | ((u64)f2bf(r2) << 32) | ((u64)f2bf(r3) << 48);
    const int q = lane & 15, dbase = w * 16 + (lane >> 4) * 4;
    *(u64*)&ctxb[((size_t)(b * SEQ + q0 + q)) * DM + h * HD + dbase] = pk;
  }
}

// ---------------------------------------------------------------- host
extern "C" void kernel_launch(void* const* d_in, const int* in_sizes, int n_in,
                              void* d_out, int out_size, void* d_ws, size_t ws_size,
                              hipStream_t stream){
  const float* q_in = (const float*)d_in[0];
  const float* k_in = (const float*)d_in[1];
  const float* v_in = (const float*)d_in[2];
  const float* Wq = (const float*)d_in[3];
  const float* bq = (const float*)d_in[4];
  const float* Wk = (const float*)d_in[5];
  const float* bk = (const float*)d_in[6];
  const float* Wv = (const float*)d_in[7];
  const float* bv = (const float*)d_in[8];
  const float* Wo = (const float*)d_in[9];
  const float* bo = (const float*)d_in[10];

  char* ws = (char*)d_ws;
  u16* Xb   = (u16*)ws;                                   // 3 x 4096x768 bf16
  u16* Wb   = (u16*)(ws + 18874368);                      // 4 x 768x768 bf16
  u16* QKVh = (u16*)(ws + 23592960);                      // Q,K head-split bf16; slot2 = V^T fp16
  u16* ctxb = (u16*)(ws + 42467328);                      // 4096x768 bf16

  cvt_kernel<<<dim3(3145728 / 1024, 3), 256, 0, stream>>>(
      q_in, k_in, v_in, nullptr, Xb, Xb + 3145728, Xb + 2 * 3145728, nullptr, 3145728);
  cvt_kernel<<<dim3(589824 / 1024, 4), 256, 0, stream>>>(
      Wq, Wk, Wv, Wo, Wb, Wb + 589824, Wb + 2 * 589824, Wb + 3 * 589824, 589824);

  gemm_bt<0><<<dim3(32, 6, 3), 256, 0, stream>>>(Xb, Wb, bq, bk, bv, QKVh, nullptr);

  attn2_kernel<<<dim3(SEQ / 16, NH, BATCH), 512, 0, stream>>>(
      QKVh, QKVh + 3145728, QKVh + 2 * 3145728, ctxb);

  gemm_bt<1><<<dim3(32, 6, 1), 256, 0, stream>>>(
      ctxb, Wb + 3 * 589824, bo, bo, bo, nullptr, (float*)d_out);
}

// Round 3
// 457.094 us; speedup vs baseline: 2.6266x; 1.4475x over previous
//
#include <hip/hip_runtime.h>
#include <hip/hip_fp16.h>
#include <stdint.h>
#include <math.h>

#define NH    12
#define SEQ   2048
#define BATCH 2
#define DM    768
#define HD    64
#define SCALEF 0.125f      // 1/sqrt(64)

typedef unsigned short u16;
typedef unsigned int   u32;
typedef unsigned long long u64;
typedef __attribute__((ext_vector_type(8))) short bf16x8;
typedef __attribute__((ext_vector_type(8))) _Float16 h16x8;
typedef __attribute__((ext_vector_type(4))) float f32x4;

__device__ __forceinline__ u16 f2bf(float f){
  u32 u = __float_as_uint(f);
  u32 r = u + 0x7fffu + ((u >> 16) & 1u);
  return (u16)(r >> 16);
}
__device__ __forceinline__ float bf2f(u16 x){ return __uint_as_float(((u32)x) << 16); }
__device__ __forceinline__ u16 f2h(float f){ return __half_as_ushort(__float2half(f)); }
__device__ __forceinline__ float h2f(u16 x){ return __half2float(__ushort_as_half(x)); }

// ---- DPP wave64 reductions (VALU pipe, no LDS) ----
__device__ __forceinline__ int dpp_sumi(int x){
  x += __builtin_amdgcn_update_dpp(0, x, 0x111, 0xf, 0xf, true);   // row_shr:1
  x += __builtin_amdgcn_update_dpp(0, x, 0x112, 0xf, 0xf, true);   // row_shr:2
  x += __builtin_amdgcn_update_dpp(0, x, 0x114, 0xf, 0xf, true);   // row_shr:4
  x += __builtin_amdgcn_update_dpp(0, x, 0x118, 0xf, 0xf, true);   // row_shr:8
  x += __builtin_amdgcn_update_dpp(0, x, 0x142, 0xa, 0xf, true);   // row_bcast:15
  x += __builtin_amdgcn_update_dpp(0, x, 0x143, 0xc, 0xf, true);   // row_bcast:31
  return __builtin_amdgcn_readlane(x, 63);                          // uniform
}
__device__ __forceinline__ int dpp_scan_incl(int x){
  x += __builtin_amdgcn_update_dpp(0, x, 0x111, 0xf, 0xf, true);
  x += __builtin_amdgcn_update_dpp(0, x, 0x112, 0xf, 0xf, true);
  x += __builtin_amdgcn_update_dpp(0, x, 0x114, 0xf, 0xf, true);
  x += __builtin_amdgcn_update_dpp(0, x, 0x118, 0xf, 0xf, true);
  x += __builtin_amdgcn_update_dpp(0, x, 0x142, 0xa, 0xf, true);
  x += __builtin_amdgcn_update_dpp(0, x, 0x143, 0xc, 0xf, true);
  return x;                                                         // inclusive prefix
}
__device__ __forceinline__ float dpp_sumf(float x){
  #define ASTEP(ctrl, rm) x += __int_as_float(__builtin_amdgcn_update_dpp(0, __float_as_int(x), ctrl, rm, 0xf, true));
  ASTEP(0x111,0xf) ASTEP(0x112,0xf) ASTEP(0x114,0xf) ASTEP(0x118,0xf) ASTEP(0x142,0xa) ASTEP(0x143,0xc)
  #undef ASTEP
  return __uint_as_float((u32)__builtin_amdgcn_readlane(__float_as_int(x), 63));
}
__device__ __forceinline__ float dpp_maxf(float x){
  #define MSTEP(ctrl, rm) { int o = __float_as_int(x); \
    x = fmaxf(x, __int_as_float(__builtin_amdgcn_update_dpp(o, o, ctrl, rm, 0xf, false))); }
  MSTEP(0x111,0xf) MSTEP(0x112,0xf) MSTEP(0x114,0xf) MSTEP(0x118,0xf) MSTEP(0x142,0xa) MSTEP(0x143,0xc)
  #undef MSTEP
  return __uint_as_float((u32)__builtin_amdgcn_readlane(__float_as_int(x), 63));
}

// swizzled fp32 score stripe sc[16][2048]: 16B-block XOR by row -> conflict-free col access
__device__ __forceinline__ int sc_off(int row, int k){
  return (row << 11) + ((((k >> 2) ^ (row & 7)) << 2) | (k & 3));
}
// swizzled fp16 prob matrix P[16][2048]
__device__ __forceinline__ int pb_off(int q, int k){
  return (q << 11) + ((((k >> 3) ^ (q & 7)) << 3) | (k & 7));
}
// swizzled psum [4 kcopies][16 q][64 d]
__device__ __forceinline__ int ps_off(int kc, int q, int d){
  return (kc << 10) + (q << 6) + ((((d >> 2) ^ q) & 15) << 2) + (d & 3);
}

// ---------------------------------------------------------------- cvt fp32->bf16
__global__ void cvt_kernel(const float* s0, const float* s1, const float* s2, const float* s3,
                           u16* d0, u16* d1, u16* d2, u16* d3, int n){
  const float* s; u16* d;
  switch (blockIdx.y){
    case 0: s = s0; d = d0; break;
    case 1: s = s1; d = d1; break;
    case 2: s = s2; d = d2; break;
    default: s = s3; d = d3; break;
  }
  int i = (blockIdx.x * 256 + threadIdx.x) * 4;
  if (i < n){
    float4 v = *(const float4*)(s + i);
    ushort4 o;
    o.x = f2bf(v.x); o.y = f2bf(v.y); o.z = f2bf(v.z); o.w = f2bf(v.w);
    *(ushort4*)(d + i) = o;
  }
}

// ---------------------------------------------------------------- GEMM  C = A @ W^T (+bias)
// MODE 0: zz=0,1 -> bf16 head-split [(b*NH+h)*SEQ+s]*HD+d ; zz=2 -> fp16 V^T [(b*NH+h)*HD+d]*SEQ+s
// MODE 1: out fp32 plain [m][n]
template<int MODE>
__global__ __launch_bounds__(256) void gemm_bt(const u16* __restrict__ Aall, const u16* __restrict__ Wall,
      const float* __restrict__ bz0, const float* __restrict__ bz1, const float* __restrict__ bz2,
      u16* __restrict__ outb, float* __restrict__ outf){
  __shared__ u16 As[128][40];
  __shared__ u16 Bs[128][40];
  const int zz = blockIdx.z;
  const u16* A = Aall + (size_t)zz * 4096 * 768;
  const u16* W = Wall + (size_t)zz * 768 * 768;
  const float* bias = (zz == 0) ? bz0 : (zz == 1 ? bz1 : bz2);
  const int m0 = blockIdx.x * 128, n0 = blockIdx.y * 128;
  const int t = threadIdx.x, lane = t & 63, wv = t >> 6;
  const int wm = wv >> 1, wn = wv & 1;
  f32x4 acc[4][4] = {};
  const int arow = t >> 1, aseg = t & 1;
  const u16* ap = A + (size_t)(m0 + arow) * 768 + aseg * 16;
  const u16* bp = W + (size_t)(n0 + arow) * 768 + aseg * 16;
  for (int kt = 0; kt < 768; kt += 32){
    uint4 av0 = *(const uint4*)(ap + kt);
    uint4 av1 = *(const uint4*)(ap + kt + 8);
    uint4 bv0 = *(const uint4*)(bp + kt);
    uint4 bv1 = *(const uint4*)(bp + kt + 8);
    __syncthreads();
    *(uint4*)&As[arow][aseg*16]     = av0;
    *(uint4*)&As[arow][aseg*16 + 8] = av1;
    *(uint4*)&Bs[arow][aseg*16]     = bv0;
    *(uint4*)&Bs[arow][aseg*16 + 8] = bv1;
    __syncthreads();
    bf16x8 af[4], bq[4];
    #pragma unroll
    for (int i = 0; i < 4; ++i) af[i] = *(const bf16x8*)&As[wm*64 + i*16 + (lane & 15)][(lane >> 4) * 8];
    #pragma unroll
    for (int i = 0; i < 4; ++i) bq[i] = *(const bf16x8*)&Bs[wn*64 + i*16 + (lane & 15)][(lane >> 4) * 8];
    #pragma unroll
    for (int mi = 0; mi < 4; ++mi)
      #pragma unroll
      for (int ni = 0; ni < 4; ++ni)
        acc[mi][ni] = __builtin_amdgcn_mfma_f32_16x16x32_bf16(af[mi], bq[ni], acc[mi][ni], 0, 0, 0);
  }
  #pragma unroll
  for (int mi = 0; mi < 4; ++mi){
    #pragma unroll
    for (int ni = 0; ni < 4; ++ni){
      const int n = n0 + wn*64 + ni*16 + (lane & 15);
      const float bval = bias[n];
      const int mbase = m0 + wm*64 + mi*16 + (lane >> 4) * 4;
      if (MODE == 0 && zz == 2){
        const int bb = mbase >> 11, ss = mbase & 2047;
        const int hh = n >> 6, dd = n & 63;
        u64 pk = 0;
        #pragma unroll
        for (int r = 0; r < 4; ++r) pk |= (u64)f2h(acc[mi][ni][r] + bval) << (16 * r);
        *(u64*)(outb + (size_t)2 * 3145728 + (((size_t)(bb * NH + hh) * HD + dd) * SEQ + ss)) = pk;
      } else if (MODE == 0){
        #pragma unroll
        for (int r = 0; r < 4; ++r){
          const int m = mbase + r;
          const int bb = m >> 11, ss = m & 2047, hh = n >> 6, dd = n & 63;
          outb[(size_t)zz * 3145728 + (((size_t)bb * NH + hh) * SEQ + ss) * HD + dd] = f2bf(acc[mi][ni][r] + bval);
        }
      } else {
        #pragma unroll
        for (int r = 0; r < 4; ++r){
          const int m = mbase + r;
          outf[(size_t)m * DM + n] = acc[mi][ni][r] + bval;
        }
      }
    }
  }
}

// ---------------------------------------------------------------- fused attention v3
// grid (SEQ/16, NH, BATCH), 1024 threads (16 waves), 16 queries/WG, 1 query per wave.
__global__ __launch_bounds__(1024, 4) void attn3_kernel(const u16* __restrict__ Qh,
      const u16* __restrict__ Kh, const u16* __restrict__ Vt, u16* __restrict__ ctxb){
  __shared__ __align__(16) u32 smem[16 * 2048 + 2048];   // 139,264 B
  float* sc   = (float*)smem;                 // [16][2048] f32 scores (swizzled)
  u16*  Pm    = (u16*)smem;                   // [16][2048] fp16 probs, overlays first 64KB
  float* psum = (float*)(smem + 16384);       // [4][16][64] f32, overlays bytes [64K,80K)
  float* s_val = (float*)(smem + 32768);      // [16][64]
  u32*  s_idx  = (u32*)(smem + 32768 + 1024); // [16][64]

  const int q0 = blockIdx.x * 16;
  const int h = blockIdx.y, b = blockIdx.z, bh = b * NH + h;
  const int t = threadIdx.x, lane = t & 63, w = t >> 6;
  const u16* Qb  = Qh + ((size_t)bh * SEQ + q0) * HD;
  const u16* Kb  = Kh + (size_t)bh * SEQ * HD;
  const u16* Vtb = Vt + (size_t)bh * HD * SEQ;

  // ---- phase A: QK^T. wave w covers keys [w*128, w*128+128), all 16 queries.
  {
    const int qcol = lane & 15;
    const bf16x8 qa0 = *(const bf16x8*)(Qb + qcol * HD + (lane >> 4) * 8);
    const bf16x8 qa1 = *(const bf16x8*)(Qb + qcol * HD + 32 + (lane >> 4) * 8);
    #pragma unroll 4
    for (int tile = 0; tile < 8; ++tile){
      const int kr = w * 128 + tile * 16 + (lane & 15);
      const bf16x8 ka0 = *(const bf16x8*)(Kb + (size_t)kr * HD + (lane >> 4) * 8);
      const bf16x8 ka1 = *(const bf16x8*)(Kb + (size_t)kr * HD + 32 + (lane >> 4) * 8);
      f32x4 d = {};
      d = __builtin_amdgcn_mfma_f32_16x16x32_bf16(ka0, qa0, d, 0, 0, 0);
      d = __builtin_amdgcn_mfma_f32_16x16x32_bf16(ka1, qa1, d, 0, 0, 0);
      const int kbase = w * 128 + tile * 16 + (lane >> 4) * 4;
      *(f32x4*)&sc[sc_off(qcol, kbase)] = d * SCALEF;
    }
  }
  __syncthreads();

  // ---- phase B: wave w loads its query row (q = w) into registers
  const int qi = q0 + w;
  u32 u[32]; float wvv[5];
  #pragma unroll
  for (int i = 0; i < 32; ++i){
    const u32 x = __float_as_uint(sc[sc_off(w, lane + 64 * i)]);
    u[i] = (x >> 31) ? ~x : (x | 0x80000000u);   // order-preserving map
  }
  const int start = (qi - 256 > 0) ? (qi - 256) : 0;
  #pragma unroll
  for (int it = 0; it < 5; ++it){
    const int c = start + lane + it * 64;
    wvv[it] = (c <= qi) ? sc[sc_off(w, c)] : -INFINITY;
  }
  __syncthreads();

  // ---- phase C: selection + softmax + P-row build (wave-private row w)
  {
    float* svals = s_val + w * 64;
    u32*  sidx   = s_idx + w * 64;

    // exact 64th-largest bit pattern via 32 probes (DPP count-reduce)
    u32 tval = 0;
    for (int bit = 31; bit >= 0; --bit){
      const u32 cand = tval | (1u << bit);
      int c = 0;
      #pragma unroll
      for (int i = 0; i < 32; ++i) c += (u[i] >= cand) ? 1 : 0;
      c = dpp_sumi(c);
      if (c >= 64){ tval = cand; if (c == 64) break; }
    }
    int ngt = 0;
    #pragma unroll
    for (int i = 0; i < 32; ++i) ngt += (u[i] > tval) ? 1 : 0;
    const int pre = dpp_scan_incl(ngt) - ngt;
    const int G = dpp_sumi(ngt);
    const int r_need = 64 - G;
    int k2 = 0;
    #pragma unroll
    for (int i = 0; i < 32; ++i){
      if (u[i] > tval){
        const u32 uu = u[i];
        svals[pre + k2] = __uint_as_float((uu & 0x80000000u) ? (uu & 0x7fffffffu) : ~uu);
        sidx[pre + k2] = lane + 64 * i; ++k2;
      }
    }
    // tie fill: lowest global index first (matches lax.top_k)
    int filled = 0;
    for (int i = 0; i < 32 && filled < r_need; ++i){
      const bool eq = (u[i] == tval);
      const u64 bal = __ballot(eq);
      const int myrank = filled + (int)__popcll(bal & ((1ull << lane) - 1ull));
      if (eq && myrank < r_need){
        svals[G + myrank] = __uint_as_float((tval & 0x80000000u) ? (tval & 0x7fffffffu) : ~tval);
        sidx[G + myrank] = lane + 64 * i;
      }
      filled += (int)__popcll(bal);
    }
    __asm__ volatile("" ::: "memory");

    // sparse softmax over exactly 64 entries (x0.5 combine folded)
    const float svv = svals[lane];
    const float m1 = dpp_maxf(svv);
    const float e1 = __expf(svv - m1);
    const float Z1 = dpp_sumf(e1);
    const float padd = e1 * (0.5f / Z1);
    const int  ksp  = (int)sidx[lane];

    // windowed causal softmax
    float wm = -INFINITY;
    #pragma unroll
    for (int it = 0; it < 5; ++it) wm = fmaxf(wm, wvv[it]);
    wm = dpp_maxf(wm);
    float zs = 0.f;
    #pragma unroll
    for (int it = 0; it < 5; ++it){
      const int c = start + lane + it * 64;
      if (c <= qi){ const float e = __expf(wvv[it] - wm); wvv[it] = e; zs += e; }
    }
    zs = dpp_sumf(zs);
    const float inv = 0.5f / zs;

    // build P row w: zero, window scatter, sparse add (all wave-private, in-order)
    {
      uint4* prow = (uint4*)(Pm + (w << 11));
      const uint4 z4 = {0u, 0u, 0u, 0u};
      #pragma unroll
      for (int i = 0; i < 4; ++i) prow[lane + i * 64] = z4;
      __asm__ volatile("" ::: "memory");
      #pragma unroll
      for (int it = 0; it < 5; ++it){
        const int c = start + lane + it * 64;
        if (c <= qi) Pm[pb_off(w, c)] = f2h(wvv[it] * inv);
      }
      __asm__ volatile("" ::: "memory");
      u16* cell = &Pm[pb_off(w, ksp)];
      *cell = f2h(h2f(*cell) + padd);
    }
  }
  __syncthreads();

  // ---- phase D: PV via fp16 MFMA. out^T[d][q] = V^T · P^T. 4-way K-split.
  {
    const int kc = w >> 2, mi = w & 3;
    f32x4 acc = {};
    #pragma unroll 4
    for (int ks = 0; ks < 16; ++ks){
      const int kk = kc * 512 + ks * 32;
      const h16x8 va = *(const h16x8*)(Vtb + (size_t)(mi * 16 + (lane & 15)) * SEQ + kk + (lane >> 4) * 8);
      const h16x8 pf = *(const h16x8*)&Pm[pb_off(lane & 15, kk + (lane >> 4) * 8)];
      acc = __builtin_amdgcn_mfma_f32_16x16x32_f16(va, pf, acc, 0, 0, 0);
    }
    const int q = lane & 15, dbase = mi * 16 + (lane >> 4) * 4;
    *(f32x4*)&psum[ps_off(kc, q, dbase)] = acc;
  }
  __syncthreads();

  // ---- phase E: reduce 4 K-copies, write bf16 ctx
  {
    const int q = t >> 6, d = t & 63;
    const float r = psum[ps_off(0, q, d)] + psum[ps_off(1, q, d)]
                  + psum[ps_off(2, q, d)] + psum[ps_off(3, q, d)];
    ctxb[((size_t)(b * SEQ + q0 + q)) * DM + h * HD + d] = f2bf(r);
  }
}

// ---------------------------------------------------------------- host
extern "C" void kernel_launch(void* const* d_in, const int* in_sizes, int n_in,
                              void* d_out, int out_size, void* d_ws, size_t ws_size,
                              hipStream_t stream){
  const float* q_in = (const float*)d_in[0];
  const float* k_in = (const float*)d_in[1];
  const float* v_in = (const float*)d_in[2];
  const float* Wq = (const float*)d_in[3];
  const float* bq = (const float*)d_in[4];
  const float* Wk = (const float*)d_in[5];
  const float* bk = (const float*)d_in[6];
  const float* Wv = (const float*)d_in[7];
  const float* bv = (const float*)d_in[8];
  const float* Wo = (const float*)d_in[9];
  const float* bo = (const float*)d_in[10];

  char* ws = (char*)d_ws;
  u16* Xb   = (u16*)ws;                                   // 3 x 4096x768 bf16
  u16* Wb   = (u16*)(ws + 18874368);                      // 4 x 768x768 bf16
  u16* QKVh = (u16*)(ws + 23592960);                      // Q,K head-split bf16; slot2 = V^T fp16
  u16* ctxb = (u16*)(ws + 42467328);                      // 4096x768 bf16

  cvt_kernel<<<dim3(3145728 / 1024, 3), 256, 0, stream>>>(
      q_in, k_in, v_in, nullptr, Xb, Xb + 3145728, Xb + 2 * 3145728, nullptr, 3145728);
  cvt_kernel<<<dim3(589824 / 1024, 4), 256, 0, stream>>>(
      Wq, Wk, Wv, Wo, Wb, Wb + 589824, Wb + 2 * 589824, Wb + 3 * 589824, 589824);

  gemm_bt<0><<<dim3(32, 6, 3), 256, 0, stream>>>(Xb, Wb, bq, bk, bv, QKVh, nullptr);

  attn3_kernel<<<dim3(SEQ / 16, NH, BATCH), 1024, 0, stream>>>(
      QKVh, QKVh + 3145728, QKVh + 2 * 3145728, ctxb);

  gemm_bt<1><<<dim3(32, 6, 1), 256, 0, stream>>>(
      ctxb, Wb + 3 * 589824, bo, bo, bo, nullptr, (float*)d_out);
}

// Round 4
// 375.680 us; speedup vs baseline: 3.1958x; 1.2167x over previous
//
#include <hip/hip_runtime.h>
#include <hip/hip_fp16.h>
#include <stdint.h>
#include <math.h>

#define NH    12
#define SEQ   2048
#define BATCH 2
#define DM    768
#define HD    64
#define SCALEF 0.125f      // 1/sqrt(64)

typedef unsigned short u16;
typedef unsigned int   u32;
typedef unsigned long long u64;
typedef __attribute__((ext_vector_type(8))) short bf16x8;
typedef __attribute__((ext_vector_type(8))) _Float16 h16x8;
typedef __attribute__((ext_vector_type(4))) float f32x4;

__device__ __forceinline__ u16 f2bf(float f){
  u32 u = __float_as_uint(f);
  u32 r = u + 0x7fffu + ((u >> 16) & 1u);
  return (u16)(r >> 16);
}
__device__ __forceinline__ float bf2f(u16 x){ return __uint_as_float(((u32)x) << 16); }
__device__ __forceinline__ u16 f2h(float f){ return __half_as_ushort(__float2half(f)); }
__device__ __forceinline__ float h2f(u16 x){ return __half2float(__ushort_as_half(x)); }

// ---- DPP wave64 reductions (VALU pipe, no LDS) ----
__device__ __forceinline__ int dpp_sumi(int x){
  x += __builtin_amdgcn_update_dpp(0, x, 0x111, 0xf, 0xf, true);   // row_shr:1
  x += __builtin_amdgcn_update_dpp(0, x, 0x112, 0xf, 0xf, true);   // row_shr:2
  x += __builtin_amdgcn_update_dpp(0, x, 0x114, 0xf, 0xf, true);   // row_shr:4
  x += __builtin_amdgcn_update_dpp(0, x, 0x118, 0xf, 0xf, true);   // row_shr:8
  x += __builtin_amdgcn_update_dpp(0, x, 0x142, 0xa, 0xf, true);   // row_bcast:15
  x += __builtin_amdgcn_update_dpp(0, x, 0x143, 0xc, 0xf, true);   // row_bcast:31
  return __builtin_amdgcn_readlane(x, 63);                          // uniform
}
__device__ __forceinline__ int dpp_scan_incl(int x){
  x += __builtin_amdgcn_update_dpp(0, x, 0x111, 0xf, 0xf, true);
  x += __builtin_amdgcn_update_dpp(0, x, 0x112, 0xf, 0xf, true);
  x += __builtin_amdgcn_update_dpp(0, x, 0x114, 0xf, 0xf, true);
  x += __builtin_amdgcn_update_dpp(0, x, 0x118, 0xf, 0xf, true);
  x += __builtin_amdgcn_update_dpp(0, x, 0x142, 0xa, 0xf, true);
  x += __builtin_amdgcn_update_dpp(0, x, 0x143, 0xc, 0xf, true);
  return x;
}
__device__ __forceinline__ float dpp_sumf(float x){
  #define ASTEP(ctrl, rm) x += __int_as_float(__builtin_amdgcn_update_dpp(0, __float_as_int(x), ctrl, rm, 0xf, true));
  ASTEP(0x111,0xf) ASTEP(0x112,0xf) ASTEP(0x114,0xf) ASTEP(0x118,0xf) ASTEP(0x142,0xa) ASTEP(0x143,0xc)
  #undef ASTEP
  return __uint_as_float((u32)__builtin_amdgcn_readlane(__float_as_int(x), 63));
}
__device__ __forceinline__ float dpp_maxf(float x){
  #define MSTEP(ctrl, rm) { int o = __float_as_int(x); \
    x = fmaxf(x, __int_as_float(__builtin_amdgcn_update_dpp(o, o, ctrl, rm, 0xf, false))); }
  MSTEP(0x111,0xf) MSTEP(0x112,0xf) MSTEP(0x114,0xf) MSTEP(0x118,0xf) MSTEP(0x142,0xa) MSTEP(0x143,0xc)
  #undef MSTEP
  return __uint_as_float((u32)__builtin_amdgcn_readlane(__float_as_int(x), 63));
}

// swizzled fp16 prob matrix P[16][2048] (u16 units)
__device__ __forceinline__ int pb_off(int q, int k){
  return (q << 11) + ((((k >> 3) ^ (q & 7)) << 3) | (k & 7));
}
// swizzled psum [4 kcopies][16 q][64 d] (f32 units)
__device__ __forceinline__ int ps_off(int kc, int q, int d){
  return (kc << 10) + (q << 6) + ((((d >> 2) ^ q) & 15) << 2) + (d & 3);
}

// ---------------------------------------------------------------- cvt fp32->bf16
__global__ void cvt_kernel(const float* s0, const float* s1, const float* s2, const float* s3,
                           u16* d0, u16* d1, u16* d2, u16* d3, int n){
  const float* s; u16* d;
  switch (blockIdx.y){
    case 0: s = s0; d = d0; break;
    case 1: s = s1; d = d1; break;
    case 2: s = s2; d = d2; break;
    default: s = s3; d = d3; break;
  }
  int i = (blockIdx.x * 256 + threadIdx.x) * 4;
  if (i < n){
    float4 v = *(const float4*)(s + i);
    ushort4 o;
    o.x = f2bf(v.x); o.y = f2bf(v.y); o.z = f2bf(v.z); o.w = f2bf(v.w);
    *(ushort4*)(d + i) = o;
  }
}

// ---------------------------------------------------------------- GEMM  C = A @ W^T (+bias)
// MODE 0: zz=0,1 -> bf16 head-split [(b*NH+h)*SEQ+s]*HD+d ; zz=2 -> fp16 V^T [(b*NH+h)*HD+d]*SEQ+s
// MODE 1: out fp32 plain [m][n]
template<int MODE>
__global__ __launch_bounds__(256) void gemm_bt(const u16* __restrict__ Aall, const u16* __restrict__ Wall,
      const float* __restrict__ bz0, const float* __restrict__ bz1, const float* __restrict__ bz2,
      u16* __restrict__ outb, float* __restrict__ outf){
  __shared__ u16 As[128][40];
  __shared__ u16 Bs[128][40];
  const int zz = blockIdx.z;
  const u16* A = Aall + (size_t)zz * 4096 * 768;
  const u16* W = Wall + (size_t)zz * 768 * 768;
  const float* bias = (zz == 0) ? bz0 : (zz == 1 ? bz1 : bz2);
  const int m0 = blockIdx.x * 128, n0 = blockIdx.y * 128;
  const int t = threadIdx.x, lane = t & 63, wv = t >> 6;
  const int wm = wv >> 1, wn = wv & 1;
  f32x4 acc[4][4] = {};
  const int arow = t >> 1, aseg = t & 1;
  const u16* ap = A + (size_t)(m0 + arow) * 768 + aseg * 16;
  const u16* bp = W + (size_t)(n0 + arow) * 768 + aseg * 16;
  for (int kt = 0; kt < 768; kt += 32){
    uint4 av0 = *(const uint4*)(ap + kt);
    uint4 av1 = *(const uint4*)(ap + kt + 8);
    uint4 bv0 = *(const uint4*)(bp + kt);
    uint4 bv1 = *(const uint4*)(bp + kt + 8);
    __syncthreads();
    *(uint4*)&As[arow][aseg*16]     = av0;
    *(uint4*)&As[arow][aseg*16 + 8] = av1;
    *(uint4*)&Bs[arow][aseg*16]     = bv0;
    *(uint4*)&Bs[arow][aseg*16 + 8] = bv1;
    __syncthreads();
    bf16x8 af[4], bq[4];
    #pragma unroll
    for (int i = 0; i < 4; ++i) af[i] = *(const bf16x8*)&As[wm*64 + i*16 + (lane & 15)][(lane >> 4) * 8];
    #pragma unroll
    for (int i = 0; i < 4; ++i) bq[i] = *(const bf16x8*)&Bs[wn*64 + i*16 + (lane & 15)][(lane >> 4) * 8];
    #pragma unroll
    for (int mi = 0; mi < 4; ++mi)
      #pragma unroll
      for (int ni = 0; ni < 4; ++ni)
        acc[mi][ni] = __builtin_amdgcn_mfma_f32_16x16x32_bf16(af[mi], bq[ni], acc[mi][ni], 0, 0, 0);
  }
  #pragma unroll
  for (int mi = 0; mi < 4; ++mi){
    #pragma unroll
    for (int ni = 0; ni < 4; ++ni){
      const int n = n0 + wn*64 + ni*16 + (lane & 15);
      const float bval = bias[n];
      const int mbase = m0 + wm*64 + mi*16 + (lane >> 4) * 4;
      if (MODE == 0 && zz == 2){
        const int bb = mbase >> 11, ss = mbase & 2047;
        const int hh = n >> 6, dd = n & 63;
        u64 pk = 0;
        #pragma unroll
        for (int r = 0; r < 4; ++r) pk |= (u64)f2h(acc[mi][ni][r] + bval) << (16 * r);
        *(u64*)(outb + (size_t)2 * 3145728 + (((size_t)(bb * NH + hh) * HD + dd) * SEQ + ss)) = pk;
      } else if (MODE == 0){
        #pragma unroll
        for (int r = 0; r < 4; ++r){
          const int m = mbase + r;
          const int bb = m >> 11, ss = m & 2047, hh = n >> 6, dd = n & 63;
          outb[(size_t)zz * 3145728 + (((size_t)bb * NH + hh) * SEQ + ss) * HD + dd] = f2bf(acc[mi][ni][r] + bval);
        }
      } else {
        #pragma unroll
        for (int r = 0; r < 4; ++r){
          const int m = mbase + r;
          outf[(size_t)m * DM + n] = acc[mi][ni][r] + bval;
        }
      }
    }
  }
}

// ---------------------------------------------------------------- fused attention v4
// grid (SEQ/16, NH, BATCH), 1024 threads (16 waves), 1 query per wave.
// LDS 80 KB: fp16 score stripe [16][2048] (64 KB, swizzled, overlaid by P) + 16 KB psum/scratch.
__global__ __launch_bounds__(1024, 8) void attn4_kernel(const u16* __restrict__ Qh,
      const u16* __restrict__ Kh, const u16* __restrict__ Vt, u16* __restrict__ ctxb){
  __shared__ __align__(16) u32 smem[20480];    // 81,920 B
  u16*  Pm    = (u16*)smem;                    // [16][2048] fp16 (overlays score stripe)
  float* psum = (float*)(smem + 16384);        // [4][16][64] f32 (phase D/E)
  float* s_val = (float*)(smem + 16384);       // [16][64] (phase C, overlays psum)
  u32*  s_idx  = (u32*)(smem + 16384 + 1024);  // [16][64]

  const int q0 = blockIdx.x * 16;
  const int h = blockIdx.y, b = blockIdx.z, bh = b * NH + h;
  const int t = threadIdx.x, lane = t & 63, w = t >> 6;
  const u16* Qb  = Qh + ((size_t)bh * SEQ + q0) * HD;
  const u16* Kb  = Kh + (size_t)bh * SEQ * HD;
  const u16* Vtb = Vt + (size_t)bh * HD * SEQ;

  // ---- phase A: QK^T -> fp16 scores. wave w covers keys [w*128, w*128+128), all 16 queries.
  {
    const int qcol = lane & 15;
    const bf16x8 qa0 = *(const bf16x8*)(Qb + qcol * HD + (lane >> 4) * 8);
    const bf16x8 qa1 = *(const bf16x8*)(Qb + qcol * HD + 32 + (lane >> 4) * 8);
    #pragma unroll 4
    for (int tile = 0; tile < 8; ++tile){
      const int kr = w * 128 + tile * 16 + (lane & 15);
      const bf16x8 ka0 = *(const bf16x8*)(Kb + (size_t)kr * HD + (lane >> 4) * 8);
      const bf16x8 ka1 = *(const bf16x8*)(Kb + (size_t)kr * HD + 32 + (lane >> 4) * 8);
      f32x4 d = {};
      d = __builtin_amdgcn_mfma_f32_16x16x32_bf16(ka0, qa0, d, 0, 0, 0);
      d = __builtin_amdgcn_mfma_f32_16x16x32_bf16(ka1, qa1, d, 0, 0, 0);
      // keys kbase..kbase+3 for query qcol; pack 4 fp16, swizzled b64 store
      const int kbase = w * 128 + tile * 16 + (lane >> 4) * 4;
      const u32 lo = (u32)f2h(d[0] * SCALEF) | ((u32)f2h(d[1] * SCALEF) << 16);
      const u32 hi = (u32)f2h(d[2] * SCALEF) | ((u32)f2h(d[3] * SCALEF) << 16);
      const int off = (qcol << 10) | ((kbase >> 1) ^ (qcol << 1));
      *(u64*)(smem + off) = (u64)lo | ((u64)hi << 32);
    }
  }
  __syncthreads();

  // ---- phase B: wave w loads its query row (q = w) into registers (u16 keys)
  const int qi = q0 + w;
  const int sw = w << 1;
  u32* rowp = smem + (w << 10);
  u32 ukey[32]; float wvv[5];
  #pragma unroll
  for (int i = 0; i < 16; ++i){
    const u32 dw = rowp[(lane + 64 * i) ^ sw];
    const u32 h0 = dw & 0xffffu, h1 = dw >> 16;
    ukey[2*i]   = (h0 & 0x8000u) ? (~h0 & 0xffffu) : (h0 | 0x8000u);  // order-preserving 16-bit key
    ukey[2*i+1] = (h1 & 0x8000u) ? (~h1 & 0xffffu) : (h1 | 0x8000u);
  }
  const int start = (qi - 256 > 0) ? (qi - 256) : 0;
  #pragma unroll
  for (int it = 0; it < 5; ++it){
    const int c0 = start + lane + it * 64;
    const int c = (c0 <= qi) ? c0 : qi;
    const u32 dw = rowp[(c >> 1) ^ sw];
    const u16 hb = (c & 1) ? (u16)(dw >> 16) : (u16)(dw & 0xffffu);
    wvv[it] = (c0 <= qi) ? h2f(hb) : -INFINITY;
  }
  __asm__ volatile("" ::: "memory");

  // ---- phase C: selection + softmax + P-row build (row w is wave-private)
  {
    float* svals = s_val + w * 64;
    u32*  sidx   = s_idx + w * 64;

    // exact 64th-largest 16-bit key via 16 probes
    u32 tval = 0;
    for (int bit = 15; bit >= 0; --bit){
      const u32 cand = tval | (1u << bit);
      int c = 0;
      #pragma unroll
      for (int i = 0; i < 32; ++i) c += (ukey[i] >= cand) ? 1 : 0;
      c = dpp_sumi(c);
      if (c >= 64){ tval = cand; if (c == 64) break; }
    }
    int ngt = 0;
    #pragma unroll
    for (int i = 0; i < 32; ++i) ngt += (ukey[i] > tval) ? 1 : 0;
    const int pre = dpp_scan_incl(ngt) - ngt;
    const int G = dpp_sumi(ngt);
    const int r_need = 64 - G;
    int k2 = 0;
    #pragma unroll
    for (int i = 0; i < 32; ++i){
      if (ukey[i] > tval){
        const u32 kk = ukey[i];
        const u16 hb = (kk & 0x8000u) ? (u16)(kk & 0x7fffu) : (u16)(~kk & 0xffffu);
        svals[pre + k2] = h2f(hb);
        sidx[pre + k2] = 2 * lane + 128 * (i >> 1) + (i & 1);
        ++k2;
      }
    }
    // tie fill (approximate index order among exactly-equal fp16 keys)
    {
      const u16 thb = (tval & 0x8000u) ? (u16)(tval & 0x7fffu) : (u16)(~tval & 0xffffu);
      const float tv = h2f(thb);
      int filled = 0;
      for (int i = 0; i < 32 && filled < r_need; ++i){
        const bool eq = (ukey[i] == tval);
        const u64 bal = __ballot(eq);
        const int myrank = filled + (int)__popcll(bal & ((1ull << lane) - 1ull));
        if (eq && myrank < r_need){
          svals[G + myrank] = tv;
          sidx[G + myrank] = 2 * lane + 128 * (i >> 1) + (i & 1);
        }
        filled += (int)__popcll(bal);
      }
    }
    __asm__ volatile("" ::: "memory");

    // sparse softmax over exactly 64 entries (x0.5 combine folded)
    const float svv = svals[lane];
    const float m1 = dpp_maxf(svv);
    const float e1 = __expf(svv - m1);
    const float Z1 = dpp_sumf(e1);
    const float padd = e1 * (0.5f / Z1);
    const int  ksp  = (int)sidx[lane];

    // windowed causal softmax
    float wm = -INFINITY;
    #pragma unroll
    for (int it = 0; it < 5; ++it) wm = fmaxf(wm, wvv[it]);
    wm = dpp_maxf(wm);
    float zs = 0.f;
    #pragma unroll
    for (int it = 0; it < 5; ++it){
      const int c = start + lane + it * 64;
      if (c <= qi){ const float e = __expf(wvv[it] - wm); wvv[it] = e; zs += e; }
    }
    zs = dpp_sumf(zs);
    const float inv = 0.5f / zs;

    // build P row w in place (overwrites consumed score row): zero, window scatter, sparse add
    {
      uint4* prow = (uint4*)(Pm + (w << 11));
      const uint4 z4 = {0u, 0u, 0u, 0u};
      #pragma unroll
      for (int i = 0; i < 4; ++i) prow[lane + i * 64] = z4;
      __asm__ volatile("" ::: "memory");
      #pragma unroll
      for (int it = 0; it < 5; ++it){
        const int c = start + lane + it * 64;
        if (c <= qi) Pm[pb_off(w, c)] = f2h(wvv[it] * inv);
      }
      __asm__ volatile("" ::: "memory");
      u16* cell = &Pm[pb_off(w, ksp)];
      *cell = f2h(h2f(*cell) + padd);
    }
  }
  __syncthreads();

  // ---- phase D: PV via fp16 MFMA. out^T[d][q] = V^T · P^T. 4-way K-split.
  {
    const int kc = w >> 2, mi = w & 3;
    f32x4 acc = {};
    #pragma unroll 4
    for (int ks = 0; ks < 16; ++ks){
      const int kk = kc * 512 + ks * 32;
      const h16x8 va = *(const h16x8*)(Vtb + (size_t)(mi * 16 + (lane & 15)) * SEQ + kk + (lane >> 4) * 8);
      const h16x8 pf = *(const h16x8*)&Pm[pb_off(lane & 15, kk + (lane >> 4) * 8)];
      acc = __builtin_amdgcn_mfma_f32_16x16x32_f16(va, pf, acc, 0, 0, 0);
    }
    const int q = lane & 15, dbase = mi * 16 + (lane >> 4) * 4;
    *(f32x4*)&psum[ps_off(kc, q, dbase)] = acc;
  }
  __syncthreads();

  // ---- phase E: reduce 4 K-copies, write bf16 ctx
  {
    const int q = t >> 6, d = t & 63;
    const float r = psum[ps_off(0, q, d)] + psum[ps_off(1, q, d)]
                  + psum[ps_off(2, q, d)] + psum[ps_off(3, q, d)];
    ctxb[((size_t)(b * SEQ + q0 + q)) * DM + h * HD + d] = f2bf(r);
  }
}

// ---------------------------------------------------------------- host
extern "C" void kernel_launch(void* const* d_in, const int* in_sizes, int n_in,
                              void* d_out, int out_size, void* d_ws, size_t ws_size,
                              hipStream_t stream){
  const float* q_in = (const float*)d_in[0];
  const float* k_in = (const float*)d_in[1];
  const float* v_in = (const float*)d_in[2];
  const float* Wq = (const float*)d_in[3];
  const float* bq = (const float*)d_in[4];
  const float* Wk = (const float*)d_in[5];
  const float* bk = (const float*)d_in[6];
  const float* Wv = (const float*)d_in[7];
  const float* bv = (const float*)d_in[8];
  const float* Wo = (const float*)d_in[9];
  const float* bo = (const float*)d_in[10];

  char* ws = (char*)d_ws;
  u16* Xb   = (u16*)ws;                                   // 3 x 4096x768 bf16
  u16* Wb   = (u16*)(ws + 18874368);                      // 4 x 768x768 bf16
  u16* QKVh = (u16*)(ws + 23592960);                      // Q,K head-split bf16; slot2 = V^T fp16
  u16* ctxb = (u16*)(ws + 42467328);                      // 4096x768 bf16

  cvt_kernel<<<dim3(3145728 / 1024, 3), 256, 0, stream>>>(
      q_in, k_in, v_in, nullptr, Xb, Xb + 3145728, Xb + 2 * 3145728, nullptr, 3145728);
  cvt_kernel<<<dim3(589824 / 1024, 4), 256, 0, stream>>>(
      Wq, Wk, Wv, Wo, Wb, Wb + 589824, Wb + 2 * 589824, Wb + 3 * 589824, 589824);

  gemm_bt<0><<<dim3(32, 6, 3), 256, 0, stream>>>(Xb, Wb, bq, bk, bv, QKVh, nullptr);

  attn4_kernel<<<dim3(SEQ / 16, NH, BATCH), 1024, 0, stream>>>(
      QKVh, QKVh + 3145728, QKVh + 2 * 3145728, ctxb);

  gemm_bt<1><<<dim3(32, 6, 1), 256, 0, stream>>>(
      ctxb, Wb + 3 * 589824, bo, bo, bo, nullptr, (float*)d_out);
}

// Round 5
// 319.500 us; speedup vs baseline: 3.7578x; 1.1758x over previous
//
#include <hip/hip_runtime.h>
#include <hip/hip_fp16.h>
#include <stdint.h>
#include <math.h>

#define NH    12
#define SEQ   2048
#define BATCH 2
#define DM    768
#define HD    64
#define SCALEF 0.125f      // 1/sqrt(64)

typedef unsigned short u16;
typedef unsigned int   u32;
typedef unsigned long long u64;
typedef __attribute__((ext_vector_type(8))) short bf16x8;
typedef __attribute__((ext_vector_type(8))) _Float16 h16x8;
typedef __attribute__((ext_vector_type(4))) float f32x4;

__device__ __forceinline__ u16 f2bf(float f){
  u32 u = __float_as_uint(f);
  u32 r = u + 0x7fffu + ((u >> 16) & 1u);
  return (u16)(r >> 16);
}
__device__ __forceinline__ float bf2f(u16 x){ return __uint_as_float(((u32)x) << 16); }
__device__ __forceinline__ u16 f2h(float f){ return __half_as_ushort(__float2half(f)); }
__device__ __forceinline__ float h2f(u16 x){ return __half2float(__ushort_as_half(x)); }

// ---- DPP wave64 reductions (VALU pipe, no LDS) ----
__device__ __forceinline__ int dpp_sumi(int x){
  x += __builtin_amdgcn_update_dpp(0, x, 0x111, 0xf, 0xf, true);   // row_shr:1
  x += __builtin_amdgcn_update_dpp(0, x, 0x112, 0xf, 0xf, true);   // row_shr:2
  x += __builtin_amdgcn_update_dpp(0, x, 0x114, 0xf, 0xf, true);   // row_shr:4
  x += __builtin_amdgcn_update_dpp(0, x, 0x118, 0xf, 0xf, true);   // row_shr:8
  x += __builtin_amdgcn_update_dpp(0, x, 0x142, 0xa, 0xf, true);   // row_bcast:15
  x += __builtin_amdgcn_update_dpp(0, x, 0x143, 0xc, 0xf, true);   // row_bcast:31
  return __builtin_amdgcn_readlane(x, 63);                          // uniform
}
__device__ __forceinline__ int dpp_scan_incl(int x){
  x += __builtin_amdgcn_update_dpp(0, x, 0x111, 0xf, 0xf, true);
  x += __builtin_amdgcn_update_dpp(0, x, 0x112, 0xf, 0xf, true);
  x += __builtin_amdgcn_update_dpp(0, x, 0x114, 0xf, 0xf, true);
  x += __builtin_amdgcn_update_dpp(0, x, 0x118, 0xf, 0xf, true);
  x += __builtin_amdgcn_update_dpp(0, x, 0x142, 0xa, 0xf, true);
  x += __builtin_amdgcn_update_dpp(0, x, 0x143, 0xc, 0xf, true);
  return x;
}
__device__ __forceinline__ float dpp_sumf(float x){
  #define ASTEP(ctrl, rm) x += __int_as_float(__builtin_amdgcn_update_dpp(0, __float_as_int(x), ctrl, rm, 0xf, true));
  ASTEP(0x111,0xf) ASTEP(0x112,0xf) ASTEP(0x114,0xf) ASTEP(0x118,0xf) ASTEP(0x142,0xa) ASTEP(0x143,0xc)
  #undef ASTEP
  return __uint_as_float((u32)__builtin_amdgcn_readlane(__float_as_int(x), 63));
}
__device__ __forceinline__ float dpp_maxf(float x){
  #define MSTEP(ctrl, rm) { int o = __float_as_int(x); \
    x = fmaxf(x, __int_as_float(__builtin_amdgcn_update_dpp(o, o, ctrl, rm, 0xf, false))); }
  MSTEP(0x111,0xf) MSTEP(0x112,0xf) MSTEP(0x114,0xf) MSTEP(0x118,0xf) MSTEP(0x142,0xa) MSTEP(0x143,0xc)
  #undef MSTEP
  return __uint_as_float((u32)__builtin_amdgcn_readlane(__float_as_int(x), 63));
}

// swizzled fp16 prob matrix P[16][2048] (u16 units)
__device__ __forceinline__ int pb_off(int q, int k){
  return (q << 11) + ((((k >> 3) ^ (q & 7)) << 3) | (k & 7));
}
// swizzled psum [4 kcopies][16 q][64 d] (f32 units)
__device__ __forceinline__ int ps_off(int kc, int q, int d){
  return (kc << 10) + (q << 6) + ((((d >> 2) ^ q) & 15) << 2) + (d & 3);
}

// ---------------------------------------------------------------- cvt fp32->bf16
__global__ void cvt_kernel(const float* s0, const float* s1, const float* s2, const float* s3,
                           u16* d0, u16* d1, u16* d2, u16* d3, int n){
  const float* s; u16* d;
  switch (blockIdx.y){
    case 0: s = s0; d = d0; break;
    case 1: s = s1; d = d1; break;
    case 2: s = s2; d = d2; break;
    default: s = s3; d = d3; break;
  }
  int i = (blockIdx.x * 256 + threadIdx.x) * 4;
  if (i < n){
    float4 v = *(const float4*)(s + i);
    ushort4 o;
    o.x = f2bf(v.x); o.y = f2bf(v.y); o.z = f2bf(v.z); o.w = f2bf(v.w);
    *(ushort4*)(d + i) = o;
  }
}

// ---------------------------------------------------------------- GEMM  C = A @ W^T (+bias)
// MODE 0: zz=0,1 -> bf16 head-split [(b*NH+h)*SEQ+s]*HD+d ; zz=2 -> fp16 V^T [(b*NH+h)*HD+d]*SEQ+s
// MODE 1: out fp32 plain [m][n]
template<int MODE>
__global__ __launch_bounds__(256) void gemm_bt(const u16* __restrict__ Aall, const u16* __restrict__ Wall,
      const float* __restrict__ bz0, const float* __restrict__ bz1, const float* __restrict__ bz2,
      u16* __restrict__ outb, float* __restrict__ outf){
  __shared__ u16 As[128][40];
  __shared__ u16 Bs[128][40];
  const int zz = blockIdx.z;
  const u16* A = Aall + (size_t)zz * 4096 * 768;
  const u16* W = Wall + (size_t)zz * 768 * 768;
  const float* bias = (zz == 0) ? bz0 : (zz == 1 ? bz1 : bz2);
  const int m0 = blockIdx.x * 128, n0 = blockIdx.y * 128;
  const int t = threadIdx.x, lane = t & 63, wv = t >> 6;
  const int wm = wv >> 1, wn = wv & 1;
  f32x4 acc[4][4] = {};
  const int arow = t >> 1, aseg = t & 1;
  const u16* ap = A + (size_t)(m0 + arow) * 768 + aseg * 16;
  const u16* bp = W + (size_t)(n0 + arow) * 768 + aseg * 16;
  for (int kt = 0; kt < 768; kt += 32){
    uint4 av0 = *(const uint4*)(ap + kt);
    uint4 av1 = *(const uint4*)(ap + kt + 8);
    uint4 bv0 = *(const uint4*)(bp + kt);
    uint4 bv1 = *(const uint4*)(bp + kt + 8);
    __syncthreads();
    *(uint4*)&As[arow][aseg*16]     = av0;
    *(uint4*)&As[arow][aseg*16 + 8] = av1;
    *(uint4*)&Bs[arow][aseg*16]     = bv0;
    *(uint4*)&Bs[arow][aseg*16 + 8] = bv1;
    __syncthreads();
    bf16x8 af[4], bq[4];
    #pragma unroll
    for (int i = 0; i < 4; ++i) af[i] = *(const bf16x8*)&As[wm*64 + i*16 + (lane & 15)][(lane >> 4) * 8];
    #pragma unroll
    for (int i = 0; i < 4; ++i) bq[i] = *(const bf16x8*)&Bs[wn*64 + i*16 + (lane & 15)][(lane >> 4) * 8];
    #pragma unroll
    for (int mi = 0; mi < 4; ++mi)
      #pragma unroll
      for (int ni = 0; ni < 4; ++ni)
        acc[mi][ni] = __builtin_amdgcn_mfma_f32_16x16x32_bf16(af[mi], bq[ni], acc[mi][ni], 0, 0, 0);
  }
  #pragma unroll
  for (int mi = 0; mi < 4; ++mi){
    #pragma unroll
    for (int ni = 0; ni < 4; ++ni){
      const int n = n0 + wn*64 + ni*16 + (lane & 15);
      const float bval = bias[n];
      const int mbase = m0 + wm*64 + mi*16 + (lane >> 4) * 4;
      if (MODE == 0 && zz == 2){
        const int bb = mbase >> 11, ss = mbase & 2047;
        const int hh = n >> 6, dd = n & 63;
        u64 pk = 0;
        #pragma unroll
        for (int r = 0; r < 4; ++r) pk |= (u64)f2h(acc[mi][ni][r] + bval) << (16 * r);
        *(u64*)(outb + (size_t)2 * 3145728 + (((size_t)(bb * NH + hh) * HD + dd) * SEQ + ss)) = pk;
      } else if (MODE == 0){
        #pragma unroll
        for (int r = 0; r < 4; ++r){
          const int m = mbase + r;
          const int bb = m >> 11, ss = m & 2047, hh = n >> 6, dd = n & 63;
          outb[(size_t)zz * 3145728 + (((size_t)bb * NH + hh) * SEQ + ss) * HD + dd] = f2bf(acc[mi][ni][r] + bval);
        }
      } else {
        #pragma unroll
        for (int r = 0; r < 4; ++r){
          const int m = mbase + r;
          outf[(size_t)m * DM + n] = acc[mi][ni][r] + bval;
        }
      }
    }
  }
}

// ---------------------------------------------------------------- fused attention v5
// grid (SEQ/16, NH, BATCH), 1024 threads (16 waves), 1 query per wave.
// LDS 80 KB. Keys held PACKED (2x u16 per VGPR) -> ~40 live VGPRs, fits 64-reg/8-wave budget.
__global__ __launch_bounds__(1024, 8) void attn5_kernel(const u16* __restrict__ Qh,
      const u16* __restrict__ Kh, const u16* __restrict__ Vt, u16* __restrict__ ctxb){
  __shared__ __align__(16) u32 smem[20480];    // 81,920 B
  u16*  Pm    = (u16*)smem;                    // [16][2048] fp16 (overlays score stripe)
  float* psum = (float*)(smem + 16384);        // [4][16][64] f32 (phase D/E)
  float* s_val = (float*)(smem + 16384);       // [16][64] (phase C, overlays psum)
  u32*  s_idx  = (u32*)(smem + 16384 + 1024);  // [16][64]

  const int q0 = blockIdx.x * 16;
  const int h = blockIdx.y, b = blockIdx.z, bh = b * NH + h;
  const int t = threadIdx.x, lane = t & 63, w = t >> 6;
  const u16* Qb  = Qh + ((size_t)bh * SEQ + q0) * HD;
  const u16* Kb  = Kh + (size_t)bh * SEQ * HD;
  const u16* Vtb = Vt + (size_t)bh * HD * SEQ;

  // ---- phase A: QK^T -> fp16 scores. wave w covers keys [w*128, w*128+128), all 16 queries.
  {
    const int qcol = lane & 15;
    const bf16x8 qa0 = *(const bf16x8*)(Qb + qcol * HD + (lane >> 4) * 8);
    const bf16x8 qa1 = *(const bf16x8*)(Qb + qcol * HD + 32 + (lane >> 4) * 8);
    #pragma unroll 4
    for (int tile = 0; tile < 8; ++tile){
      const int kr = w * 128 + tile * 16 + (lane & 15);
      const bf16x8 ka0 = *(const bf16x8*)(Kb + (size_t)kr * HD + (lane >> 4) * 8);
      const bf16x8 ka1 = *(const bf16x8*)(Kb + (size_t)kr * HD + 32 + (lane >> 4) * 8);
      f32x4 d = {};
      d = __builtin_amdgcn_mfma_f32_16x16x32_bf16(ka0, qa0, d, 0, 0, 0);
      d = __builtin_amdgcn_mfma_f32_16x16x32_bf16(ka1, qa1, d, 0, 0, 0);
      const int kbase = w * 128 + tile * 16 + (lane >> 4) * 4;
      const u32 lo = (u32)f2h(d[0] * SCALEF) | ((u32)f2h(d[1] * SCALEF) << 16);
      const u32 hi = (u32)f2h(d[2] * SCALEF) | ((u32)f2h(d[3] * SCALEF) << 16);
      const int off = (qcol << 10) | ((kbase >> 1) ^ (qcol << 1));
      *(u64*)(smem + off) = (u64)lo | ((u64)hi << 32);
    }
  }
  __syncthreads();

  // ---- phase B: wave w loads its query row (q = w) as PACKED order-preserving u16 keys
  const int qi = q0 + w;
  const int sw = w << 1;
  u32* rowp = smem + (w << 10);
  u32 ukp[16]; float wvv[5];
  #pragma unroll
  for (int i = 0; i < 16; ++i){
    const u32 dw = rowp[(lane + 64 * i) ^ sw];
    const u32 s = (dw >> 15) & 0x00010001u;
    ukp[i] = dw ^ (0x80008000u | (s * 0x7fffu));   // per-half: neg -> ~x, pos -> x|0x8000
  }
  const int start = (qi - 256 > 0) ? (qi - 256) : 0;
  #pragma unroll
  for (int it = 0; it < 5; ++it){
    const int c0 = start + lane + it * 64;
    const int c = (c0 <= qi) ? c0 : qi;
    const u32 dw = rowp[(c >> 1) ^ sw];
    const u16 hb = (c & 1) ? (u16)(dw >> 16) : (u16)(dw & 0xffffu);
    wvv[it] = (c0 <= qi) ? h2f(hb) : -INFINITY;
  }
  __asm__ volatile("" ::: "memory");

  // ---- phase C: selection + softmax + P-row build (row w is wave-private)
  {
    float* svals = s_val + w * 64;
    u32*  sidx   = s_idx + w * 64;

    // exact 64th-largest 16-bit key via 16 probes (packed extraction)
    u32 tval = 0;
    for (int bit = 15; bit >= 0; --bit){
      const u32 cand = tval | (1u << bit);
      int c = 0;
      #pragma unroll
      for (int i = 0; i < 16; ++i){
        c += ((ukp[i] & 0xffffu) >= cand) ? 1 : 0;
        c += ((ukp[i] >> 16) >= cand) ? 1 : 0;
      }
      c = dpp_sumi(c);
      if (c >= 64){ tval = cand; if (c == 64) break; }
    }
    int ngt = 0;
    #pragma unroll
    for (int i = 0; i < 16; ++i){
      ngt += ((ukp[i] & 0xffffu) > tval) ? 1 : 0;
      ngt += ((ukp[i] >> 16) > tval) ? 1 : 0;
    }
    const int pre = dpp_scan_incl(ngt) - ngt;
    const int G = dpp_sumi(ngt);
    const int r_need = 64 - G;
    int k2 = 0;
    #pragma unroll
    for (int i = 0; i < 16; ++i){
      #pragma unroll
      for (int hh = 0; hh < 2; ++hh){
        const u32 kk = hh ? (ukp[i] >> 16) : (ukp[i] & 0xffffu);
        if (kk > tval){
          const u16 hb = (kk & 0x8000u) ? (u16)(kk & 0x7fffu) : (u16)(~kk & 0xffffu);
          svals[pre + k2] = h2f(hb);
          sidx[pre + k2] = 2 * lane + 128 * i + hh;
          ++k2;
        }
      }
    }
    // tie fill (approximate index order among exactly-equal fp16 keys)
    {
      const u16 thb = (tval & 0x8000u) ? (u16)(tval & 0x7fffu) : (u16)(~tval & 0xffffu);
      const float tv = h2f(thb);
      int filled = 0;
      for (int i = 0; i < 16 && filled < r_need; ++i){
        #pragma unroll
        for (int hh = 0; hh < 2; ++hh){
          const u32 kk = hh ? (ukp[i] >> 16) : (ukp[i] & 0xffffu);
          const bool eq = (kk == tval);
          const u64 bal = __ballot(eq);
          const int myrank = filled + (int)__popcll(bal & ((1ull << lane) - 1ull));
          if (eq && myrank < r_need){
            svals[G + myrank] = tv;
            sidx[G + myrank] = 2 * lane + 128 * i + hh;
          }
          filled += (int)__popcll(bal);
        }
      }
    }
    __asm__ volatile("" ::: "memory");

    // sparse softmax over exactly 64 entries (x0.5 combine folded)
    const float svv = svals[lane];
    const float m1 = dpp_maxf(svv);
    const float e1 = __expf(svv - m1);
    const float Z1 = dpp_sumf(e1);
    const float padd = e1 * (0.5f / Z1);
    const int  ksp  = (int)sidx[lane];

    // windowed causal softmax
    float wm = -INFINITY;
    #pragma unroll
    for (int it = 0; it < 5; ++it) wm = fmaxf(wm, wvv[it]);
    wm = dpp_maxf(wm);
    float zs = 0.f;
    #pragma unroll
    for (int it = 0; it < 5; ++it){
      const int c = start + lane + it * 64;
      if (c <= qi){ const float e = __expf(wvv[it] - wm); wvv[it] = e; zs += e; }
    }
    zs = dpp_sumf(zs);
    const float inv = 0.5f / zs;

    // build P row w in place (overwrites consumed score row): zero, window scatter, sparse add
    {
      uint4* prow = (uint4*)(Pm + (w << 11));
      const uint4 z4 = {0u, 0u, 0u, 0u};
      #pragma unroll
      for (int i = 0; i < 4; ++i) prow[lane + i * 64] = z4;
      __asm__ volatile("" ::: "memory");
      #pragma unroll
      for (int it = 0; it < 5; ++it){
        const int c = start + lane + it * 64;
        if (c <= qi) Pm[pb_off(w, c)] = f2h(wvv[it] * inv);
      }
      __asm__ volatile("" ::: "memory");
      u16* cell = &Pm[pb_off(w, ksp)];
      *cell = f2h(h2f(*cell) + padd);
    }
  }
  __syncthreads();

  // ---- phase D: PV via fp16 MFMA. out^T[d][q] = V^T · P^T. 4-way K-split.
  {
    const int kc = w >> 2, mi = w & 3;
    f32x4 acc = {};
    #pragma unroll 4
    for (int ks = 0; ks < 16; ++ks){
      const int kk = kc * 512 + ks * 32;
      const h16x8 va = *(const h16x8*)(Vtb + (size_t)(mi * 16 + (lane & 15)) * SEQ + kk + (lane >> 4) * 8);
      const h16x8 pf = *(const h16x8*)&Pm[pb_off(lane & 15, kk + (lane >> 4) * 8)];
      acc = __builtin_amdgcn_mfma_f32_16x16x32_f16(va, pf, acc, 0, 0, 0);
    }
    const int q = lane & 15, dbase = mi * 16 + (lane >> 4) * 4;
    *(f32x4*)&psum[ps_off(kc, q, dbase)] = acc;
  }
  __syncthreads();

  // ---- phase E: reduce 4 K-copies, write bf16 ctx
  {
    const int q = t >> 6, d = t & 63;
    const float r = psum[ps_off(0, q, d)] + psum[ps_off(1, q, d)]
                  + psum[ps_off(2, q, d)] + psum[ps_off(3, q, d)];
    ctxb[((size_t)(b * SEQ + q0 + q)) * DM + h * HD + d] = f2bf(r);
  }
}

// ---------------------------------------------------------------- host
extern "C" void kernel_launch(void* const* d_in, const int* in_sizes, int n_in,
                              void* d_out, int out_size, void* d_ws, size_t ws_size,
                              hipStream_t stream){
  const float* q_in = (const float*)d_in[0];
  const float* k_in = (const float*)d_in[1];
  const float* v_in = (const float*)d_in[2];
  const float* Wq = (const float*)d_in[3];
  const float* bq = (const float*)d_in[4];
  const float* Wk = (const float*)d_in[5];
  const float* bk = (const float*)d_in[6];
  const float* Wv = (const float*)d_in[7];
  const float* bv = (const float*)d_in[8];
  const float* Wo = (const float*)d_in[9];
  const float* bo = (const float*)d_in[10];

  char* ws = (char*)d_ws;
  u16* Xb   = (u16*)ws;                                   // 3 x 4096x768 bf16
  u16* Wb   = (u16*)(ws + 18874368);                      // 4 x 768x768 bf16
  u16* QKVh = (u16*)(ws + 23592960);                      // Q,K head-split bf16; slot2 = V^T fp16
  u16* ctxb = (u16*)(ws + 42467328);                      // 4096x768 bf16

  cvt_kernel<<<dim3(3145728 / 1024, 3), 256, 0, stream>>>(
      q_in, k_in, v_in, nullptr, Xb, Xb + 3145728, Xb + 2 * 3145728, nullptr, 3145728);
  cvt_kernel<<<dim3(589824 / 1024, 4), 256, 0, stream>>>(
      Wq, Wk, Wv, Wo, Wb, Wb + 589824, Wb + 2 * 589824, Wb + 3 * 589824, 589824);

  gemm_bt<0><<<dim3(32, 6, 3), 256, 0, stream>>>(Xb, Wb, bq, bk, bv, QKVh, nullptr);

  attn5_kernel<<<dim3(SEQ / 16, NH, BATCH), 1024, 0, stream>>>(
      QKVh, QKVh + 3145728, QKVh + 2 * 3145728, ctxb);

  gemm_bt<1><<<dim3(32, 6, 1), 256, 0, stream>>>(
      ctxb, Wb + 3 * 589824, bo, bo, bo, nullptr, (float*)d_out);
}

// Round 6
// 313.510 us; speedup vs baseline: 3.8296x; 1.0191x over previous
//
#include <hip/hip_runtime.h>
#include <hip/hip_fp16.h>
#include <stdint.h>
#include <math.h>

#define NH    12
#define SEQ   2048
#define BATCH 2
#define DM    768
#define HD    64
#define SCALEF 0.125f      // 1/sqrt(64)

typedef unsigned short u16;
typedef unsigned int   u32;
typedef unsigned long long u64;
typedef __attribute__((ext_vector_type(8))) short bf16x8;
typedef __attribute__((ext_vector_type(8))) _Float16 h16x8;
typedef __attribute__((ext_vector_type(4))) float f32x4;

__device__ __forceinline__ u16 f2bf(float f){
  u32 u = __float_as_uint(f);
  u32 r = u + 0x7fffu + ((u >> 16) & 1u);
  return (u16)(r >> 16);
}
__device__ __forceinline__ float bf2f(u16 x){ return __uint_as_float(((u32)x) << 16); }
__device__ __forceinline__ u16 f2h(float f){ return __half_as_ushort(__float2half(f)); }
__device__ __forceinline__ float h2f(u16 x){ return __half2float(__ushort_as_half(x)); }

// ---- DPP wave64 reductions (VALU pipe, no LDS) ----
__device__ __forceinline__ int dpp_sumi(int x){
  x += __builtin_amdgcn_update_dpp(0, x, 0x111, 0xf, 0xf, true);   // row_shr:1
  x += __builtin_amdgcn_update_dpp(0, x, 0x112, 0xf, 0xf, true);   // row_shr:2
  x += __builtin_amdgcn_update_dpp(0, x, 0x114, 0xf, 0xf, true);   // row_shr:4
  x += __builtin_amdgcn_update_dpp(0, x, 0x118, 0xf, 0xf, true);   // row_shr:8
  x += __builtin_amdgcn_update_dpp(0, x, 0x142, 0xa, 0xf, true);   // row_bcast:15
  x += __builtin_amdgcn_update_dpp(0, x, 0x143, 0xc, 0xf, true);   // row_bcast:31
  return __builtin_amdgcn_readlane(x, 63);                          // uniform
}
__device__ __forceinline__ int dpp_scan_incl(int x){
  x += __builtin_amdgcn_update_dpp(0, x, 0x111, 0xf, 0xf, true);
  x += __builtin_amdgcn_update_dpp(0, x, 0x112, 0xf, 0xf, true);
  x += __builtin_amdgcn_update_dpp(0, x, 0x114, 0xf, 0xf, true);
  x += __builtin_amdgcn_update_dpp(0, x, 0x118, 0xf, 0xf, true);
  x += __builtin_amdgcn_update_dpp(0, x, 0x142, 0xa, 0xf, true);
  x += __builtin_amdgcn_update_dpp(0, x, 0x143, 0xc, 0xf, true);
  return x;
}
__device__ __forceinline__ float dpp_sumf(float x){
  #define ASTEP(ctrl, rm) x += __int_as_float(__builtin_amdgcn_update_dpp(0, __float_as_int(x), ctrl, rm, 0xf, true));
  ASTEP(0x111,0xf) ASTEP(0x112,0xf) ASTEP(0x114,0xf) ASTEP(0x118,0xf) ASTEP(0x142,0xa) ASTEP(0x143,0xc)
  #undef ASTEP
  return __uint_as_float((u32)__builtin_amdgcn_readlane(__float_as_int(x), 63));
}
__device__ __forceinline__ float dpp_maxf(float x){
  #define MSTEP(ctrl, rm) { int o = __float_as_int(x); \
    x = fmaxf(x, __int_as_float(__builtin_amdgcn_update_dpp(o, o, ctrl, rm, 0xf, false))); }
  MSTEP(0x111,0xf) MSTEP(0x112,0xf) MSTEP(0x114,0xf) MSTEP(0x118,0xf) MSTEP(0x142,0xa) MSTEP(0x143,0xc)
  #undef MSTEP
  return __uint_as_float((u32)__builtin_amdgcn_readlane(__float_as_int(x), 63));
}

// swizzled fp16 prob matrix P[16][2048] (u16 units)
__device__ __forceinline__ int pb_off(int q, int k){
  return (q << 11) + ((((k >> 3) ^ (q & 7)) << 3) | (k & 7));
}
// swizzled psum [4 kcopies][16 q][64 d] (f32 units)
__device__ __forceinline__ int ps_off(int kc, int q, int d){
  return (kc << 10) + (q << 6) + ((((d >> 2) ^ q) & 15) << 2) + (d & 3);
}

// ---------------------------------------------------------------- cvt fp32->bf16
__global__ void cvt_kernel(const float* s0, const float* s1, const float* s2, const float* s3,
                           u16* d0, u16* d1, u16* d2, u16* d3, int n){
  const float* s; u16* d;
  switch (blockIdx.y){
    case 0: s = s0; d = d0; break;
    case 1: s = s1; d = d1; break;
    case 2: s = s2; d = d2; break;
    default: s = s3; d = d3; break;
  }
  int i = (blockIdx.x * 256 + threadIdx.x) * 4;
  if (i < n){
    float4 v = *(const float4*)(s + i);
    ushort4 o;
    o.x = f2bf(v.x); o.y = f2bf(v.y); o.z = f2bf(v.z); o.w = f2bf(v.w);
    *(ushort4*)(d + i) = o;
  }
}

// ---------------------------------------------------------------- GEMM  C = A @ W^T (+bias)
// MODE 0: zz=0,1 -> bf16 head-split [(b*NH+h)*SEQ+s]*HD+d ; zz=2 -> fp16 V^T [(b*NH+h)*HD+d]*SEQ+s
// MODE 1: out fp32 plain [m][n]
template<int MODE>
__global__ __launch_bounds__(256) void gemm_bt(const u16* __restrict__ Aall, const u16* __restrict__ Wall,
      const float* __restrict__ bz0, const float* __restrict__ bz1, const float* __restrict__ bz2,
      u16* __restrict__ outb, float* __restrict__ outf){
  __shared__ u16 As[128][40];
  __shared__ u16 Bs[128][40];
  const int zz = blockIdx.z;
  const u16* A = Aall + (size_t)zz * 4096 * 768;
  const u16* W = Wall + (size_t)zz * 768 * 768;
  const float* bias = (zz == 0) ? bz0 : (zz == 1 ? bz1 : bz2);
  const int m0 = blockIdx.x * 128, n0 = blockIdx.y * 128;
  const int t = threadIdx.x, lane = t & 63, wv = t >> 6;
  const int wm = wv >> 1, wn = wv & 1;
  f32x4 acc[4][4] = {};
  const int arow = t >> 1, aseg = t & 1;
  const u16* ap = A + (size_t)(m0 + arow) * 768 + aseg * 16;
  const u16* bp = W + (size_t)(n0 + arow) * 768 + aseg * 16;
  for (int kt = 0; kt < 768; kt += 32){
    uint4 av0 = *(const uint4*)(ap + kt);
    uint4 av1 = *(const uint4*)(ap + kt + 8);
    uint4 bv0 = *(const uint4*)(bp + kt);
    uint4 bv1 = *(const uint4*)(bp + kt + 8);
    __syncthreads();
    *(uint4*)&As[arow][aseg*16]     = av0;
    *(uint4*)&As[arow][aseg*16 + 8] = av1;
    *(uint4*)&Bs[arow][aseg*16]     = bv0;
    *(uint4*)&Bs[arow][aseg*16 + 8] = bv1;
    __syncthreads();
    bf16x8 af[4], bq[4];
    #pragma unroll
    for (int i = 0; i < 4; ++i) af[i] = *(const bf16x8*)&As[wm*64 + i*16 + (lane & 15)][(lane >> 4) * 8];
    #pragma unroll
    for (int i = 0; i < 4; ++i) bq[i] = *(const bf16x8*)&Bs[wn*64 + i*16 + (lane & 15)][(lane >> 4) * 8];
    #pragma unroll
    for (int mi = 0; mi < 4; ++mi)
      #pragma unroll
      for (int ni = 0; ni < 4; ++ni)
        acc[mi][ni] = __builtin_amdgcn_mfma_f32_16x16x32_bf16(af[mi], bq[ni], acc[mi][ni], 0, 0, 0);
  }
  #pragma unroll
  for (int mi = 0; mi < 4; ++mi){
    #pragma unroll
    for (int ni = 0; ni < 4; ++ni){
      const int n = n0 + wn*64 + ni*16 + (lane & 15);
      const float bval = bias[n];
      const int mbase = m0 + wm*64 + mi*16 + (lane >> 4) * 4;
      if (MODE == 0 && zz == 2){
        const int bb = mbase >> 11, ss = mbase & 2047;
        const int hh = n >> 6, dd = n & 63;
        u64 pk = 0;
        #pragma unroll
        for (int r = 0; r < 4; ++r) pk |= (u64)f2h(acc[mi][ni][r] + bval) << (16 * r);
        *(u64*)(outb + (size_t)2 * 3145728 + (((size_t)(bb * NH + hh) * HD + dd) * SEQ + ss)) = pk;
      } else if (MODE == 0){
        #pragma unroll
        for (int r = 0; r < 4; ++r){
          const int m = mbase + r;
          const int bb = m >> 11, ss = m & 2047, hh = n >> 6, dd = n & 63;
          outb[(size_t)zz * 3145728 + (((size_t)bb * NH + hh) * SEQ + ss) * HD + dd] = f2bf(acc[mi][ni][r] + bval);
        }
      } else {
        #pragma unroll
        for (int r = 0; r < 4; ++r){
          const int m = mbase + r;
          outf[(size_t)m * DM + n] = acc[mi][ni][r] + bval;
        }
      }
    }
  }
}

// ---------------------------------------------------------------- fused attention v6
// grid (SEQ/16, NH, BATCH), 1024 threads (16 waves), 1 query per wave.
// LDS 80 KB. Selection via 2-pass LDS-histogram exact rank-64 (replaces 16-probe search).
__global__ __launch_bounds__(1024, 8) void attn6_kernel(const u16* __restrict__ Qh,
      const u16* __restrict__ Kh, const u16* __restrict__ Vt, u16* __restrict__ ctxb){
  __shared__ __align__(16) u32 smem[20480];    // 81,920 B
  u16*  Pm    = (u16*)smem;                    // [16][2048] fp16 (overlays score stripe)
  float* psum = (float*)(smem + 16384);        // [4][16][64] f32 (phase D/E, overlays hists)

  const int q0 = blockIdx.x * 16;
  const int h = blockIdx.y, b = blockIdx.z, bh = b * NH + h;
  const int t = threadIdx.x, lane = t & 63, w = t >> 6;
  const u16* Qb  = Qh + ((size_t)bh * SEQ + q0) * HD;
  const u16* Kb  = Kh + (size_t)bh * SEQ * HD;
  const u16* Vtb = Vt + (size_t)bh * HD * SEQ;

  // ---- phase A: QK^T -> fp16 scores. wave w covers keys [w*128, w*128+128), all 16 queries.
  {
    const int qcol = lane & 15;
    const bf16x8 qa0 = *(const bf16x8*)(Qb + qcol * HD + (lane >> 4) * 8);
    const bf16x8 qa1 = *(const bf16x8*)(Qb + qcol * HD + 32 + (lane >> 4) * 8);
    #pragma unroll 4
    for (int tile = 0; tile < 8; ++tile){
      const int kr = w * 128 + tile * 16 + (lane & 15);
      const bf16x8 ka0 = *(const bf16x8*)(Kb + (size_t)kr * HD + (lane >> 4) * 8);
      const bf16x8 ka1 = *(const bf16x8*)(Kb + (size_t)kr * HD + 32 + (lane >> 4) * 8);
      f32x4 d = {};
      d = __builtin_amdgcn_mfma_f32_16x16x32_bf16(ka0, qa0, d, 0, 0, 0);
      d = __builtin_amdgcn_mfma_f32_16x16x32_bf16(ka1, qa1, d, 0, 0, 0);
      const int kbase = w * 128 + tile * 16 + (lane >> 4) * 4;
      const u32 lo = (u32)f2h(d[0] * SCALEF) | ((u32)f2h(d[1] * SCALEF) << 16);
      const u32 hi = (u32)f2h(d[2] * SCALEF) | ((u32)f2h(d[3] * SCALEF) << 16);
      const int off = (qcol << 10) | ((kbase >> 1) ^ (qcol << 1));
      *(u64*)(smem + off) = (u64)lo | ((u64)hi << 32);
    }
  }
  __syncthreads();

  // ---- phase B: wave w loads its query row (q = w) as PACKED order-preserving u16 keys
  const int qi = q0 + w;
  const int sw = w << 1;
  u32* rowp = smem + (w << 10);
  u32* hw   = smem + 16384 + (w << 8);   // wave-private 1KB: hist[256] -> later s_val/s_idx
  u32 ukp[16];
  #pragma unroll
  for (int i = 0; i < 16; ++i){
    const u32 dw = rowp[(lane + 64 * i) ^ sw];
    const u32 s = (dw >> 15) & 0x00010001u;
    ukp[i] = dw ^ (0x80008000u | (s * 0x7fffu));   // per-half: neg -> ~x, pos -> x|0x8000
  }
  __asm__ volatile("" ::: "memory");

  // ---- phase C: exact rank-64 selection via 2-pass histogram (wave-private)
  int tb, G_byte;
  const uint4 z4 = {0u, 0u, 0u, 0u};
  {
    // pass 1: top-byte histogram
    *(uint4*)&hw[lane << 2] = z4;
    __asm__ volatile("s_waitcnt lgkmcnt(0)" ::: "memory");
    #pragma unroll
    for (int i = 0; i < 16; ++i){
      atomicAdd(&hw[(ukp[i] >> 8) & 0xffu], 1u);   // lo half top byte
      atomicAdd(&hw[ukp[i] >> 24], 1u);            // hi half top byte
    }
    __asm__ volatile("s_waitcnt lgkmcnt(0)" ::: "memory");
    const uint4 hv = *(const uint4*)&hw[lane << 2];
    const int s_l = (int)(hv.x + hv.y + hv.z + hv.w);
    const int incl = dpp_scan_incl(s_l);
    const int ab3 = 2048 - incl;              // keys in bins above 4*lane+3
    const int ab2 = ab3 + (int)hv.w;
    const int ab1 = ab2 + (int)hv.z;
    const int ab0 = ab1 + (int)hv.y;
    int pk = 0;
    if      (ab3 < 64 && ab3 + (int)hv.w >= 64) pk = ((((lane << 2) + 3) << 16) | ab3);
    else if (ab2 < 64 && ab2 + (int)hv.z >= 64) pk = ((((lane << 2) + 2) << 16) | ab2);
    else if (ab1 < 64 && ab1 + (int)hv.y >= 64) pk = ((((lane << 2) + 1) << 16) | ab1);
    else if (ab0 < 64 && ab0 + (int)hv.x >= 64) pk = ((((lane << 2) + 0) << 16) | ab0);
    const int win = dpp_sumi(pk);
    tb = win >> 16; G_byte = win & 0xffff;
  }
  u32 tval; int G, r_need;
  {
    // pass 2: low-byte histogram within top-byte bucket tb
    *(uint4*)&hw[lane << 2] = z4;
    __asm__ volatile("s_waitcnt lgkmcnt(0)" ::: "memory");
    #pragma unroll
    for (int i = 0; i < 16; ++i){
      const u32 lo = ukp[i] & 0xffffu;
      const u32 hi = ukp[i] >> 16;
      if ((int)(lo >> 8) == tb) atomicAdd(&hw[lo & 0xffu], 1u);
      if ((int)(hi >> 8) == tb) atomicAdd(&hw[hi & 0xffu], 1u);
    }
    __asm__ volatile("s_waitcnt lgkmcnt(0)" ::: "memory");
    const uint4 hv = *(const uint4*)&hw[lane << 2];
    const int s_l = (int)(hv.x + hv.y + hv.z + hv.w);
    const int incl = dpp_scan_incl(s_l);
    const int tot2 = __builtin_amdgcn_readlane(incl, 63);
    const int ab3 = G_byte + tot2 - incl;
    const int ab2 = ab3 + (int)hv.w;
    const int ab1 = ab2 + (int)hv.z;
    const int ab0 = ab1 + (int)hv.y;
    int pk = 0;
    if      (ab3 < 64 && ab3 + (int)hv.w >= 64) pk = ((((lane << 2) + 3) << 16) | ab3);
    else if (ab2 < 64 && ab2 + (int)hv.z >= 64) pk = ((((lane << 2) + 2) << 16) | ab2);
    else if (ab1 < 64 && ab1 + (int)hv.y >= 64) pk = ((((lane << 2) + 1) << 16) | ab1);
    else if (ab0 < 64 && ab0 + (int)hv.x >= 64) pk = ((((lane << 2) + 0) << 16) | ab0);
    const int win = dpp_sumi(pk);
    const int lb = win >> 16;
    G = win & 0xffff;
    tval = (u32)((tb << 8) | lb);
    r_need = 64 - G;
  }

  // ---- extraction + tie fill + softmax + P build (identical math to v5)
  {
    float* svals = (float*)hw;        // overlays consumed histogram (dwords 0..63)
    u32*  sidx   = hw + 64;           // dwords 64..127
    int ngt = 0;
    #pragma unroll
    for (int i = 0; i < 16; ++i){
      ngt += ((ukp[i] & 0xffffu) > tval) ? 1 : 0;
      ngt += ((ukp[i] >> 16) > tval) ? 1 : 0;
    }
    const int pre = dpp_scan_incl(ngt) - ngt;
    int k2 = 0;
    #pragma unroll
    for (int i = 0; i < 16; ++i){
      #pragma unroll
      for (int hh = 0; hh < 2; ++hh){
        const u32 kk = hh ? (ukp[i] >> 16) : (ukp[i] & 0xffffu);
        if (kk > tval){
          const u16 hb = (kk & 0x8000u) ? (u16)(kk & 0x7fffu) : (u16)(~kk & 0xffffu);
          svals[pre + k2] = h2f(hb);
          sidx[pre + k2] = 2 * lane + 128 * i + hh;
          ++k2;
        }
      }
    }
    // tie fill (lowest global index first among exactly-equal fp16 keys)
    {
      const u16 thb = (tval & 0x8000u) ? (u16)(tval & 0x7fffu) : (u16)(~tval & 0xffffu);
      const float tv = h2f(thb);
      int filled = 0;
      for (int i = 0; i < 16 && filled < r_need; ++i){
        #pragma unroll
        for (int hh = 0; hh < 2; ++hh){
          const u32 kk = hh ? (ukp[i] >> 16) : (ukp[i] & 0xffffu);
          const bool eq = (kk == tval);
          const u64 bal = __ballot(eq);
          const int myrank = filled + (int)__popcll(bal & ((1ull << lane) - 1ull));
          if (eq && myrank < r_need){
            svals[G + myrank] = tv;
            sidx[G + myrank] = 2 * lane + 128 * i + hh;
          }
          filled += (int)__popcll(bal);
        }
      }
    }
    __asm__ volatile("" ::: "memory");

    // sparse softmax over exactly 64 entries (x0.5 combine folded)
    const float svv = svals[lane];
    const float m1 = dpp_maxf(svv);
    const float e1 = __expf(svv - m1);
    const float Z1 = dpp_sumf(e1);
    const float padd = e1 * (0.5f / Z1);
    const int  ksp  = (int)sidx[lane];

    // windowed causal branch: load window scores, softmax
    const int start = (qi - 256 > 0) ? (qi - 256) : 0;
    float wvv[5];
    #pragma unroll
    for (int it = 0; it < 5; ++it){
      const int c0 = start + lane + it * 64;
      const int c = (c0 <= qi) ? c0 : qi;
      const u32 dw = rowp[(c >> 1) ^ sw];
      const u16 hb = (c & 1) ? (u16)(dw >> 16) : (u16)(dw & 0xffffu);
      wvv[it] = (c0 <= qi) ? h2f(hb) : -INFINITY;
    }
    float wm = -INFINITY;
    #pragma unroll
    for (int it = 0; it < 5; ++it) wm = fmaxf(wm, wvv[it]);
    wm = dpp_maxf(wm);
    float zs = 0.f;
    #pragma unroll
    for (int it = 0; it < 5; ++it){
      const int c = start + lane + it * 64;
      if (c <= qi){ const float e = __expf(wvv[it] - wm); wvv[it] = e; zs += e; }
    }
    zs = dpp_sumf(zs);
    const float inv = 0.5f / zs;

    // build P row w in place: zero, window scatter, sparse add (wave-private, in-order)
    {
      uint4* prow = (uint4*)(Pm + (w << 11));
      #pragma unroll
      for (int i = 0; i < 4; ++i) prow[lane + i * 64] = z4;
      __asm__ volatile("" ::: "memory");
      #pragma unroll
      for (int it = 0; it < 5; ++it){
        const int c = start + lane + it * 64;
        if (c <= qi) Pm[pb_off(w, c)] = f2h(wvv[it] * inv);
      }
      __asm__ volatile("" ::: "memory");
      u16* cell = &Pm[pb_off(w, ksp)];
      *cell = f2h(h2f(*cell) + padd);
    }
  }
  __syncthreads();

  // ---- phase D: PV via fp16 MFMA. out^T[d][q] = V^T · P^T. 4-way K-split.
  {
    const int kc = w >> 2, mi = w & 3;
    f32x4 acc = {};
    #pragma unroll 4
    for (int ks = 0; ks < 16; ++ks){
      const int kk = kc * 512 + ks * 32;
      const h16x8 va = *(const h16x8*)(Vtb + (size_t)(mi * 16 + (lane & 15)) * SEQ + kk + (lane >> 4) * 8);
      const h16x8 pf = *(const h16x8*)&Pm[pb_off(lane & 15, kk + (lane >> 4) * 8)];
      acc = __builtin_amdgcn_mfma_f32_16x16x32_f16(va, pf, acc, 0, 0, 0);
    }
    const int q = lane & 15, dbase = mi * 16 + (lane >> 4) * 4;
    *(f32x4*)&psum[ps_off(kc, q, dbase)] = acc;
  }
  __syncthreads();

  // ---- phase E: reduce 4 K-copies, write bf16 ctx
  {
    const int q = t >> 6, d = t & 63;
    const float r = psum[ps_off(0, q, d)] + psum[ps_off(1, q, d)]
                  + psum[ps_off(2, q, d)] + psum[ps_off(3, q, d)];
    ctxb[((size_t)(b * SEQ + q0 + q)) * DM + h * HD + d] = f2bf(r);
  }
}

// ---------------------------------------------------------------- host
extern "C" void kernel_launch(void* const* d_in, const int* in_sizes, int n_in,
                              void* d_out, int out_size, void* d_ws, size_t ws_size,
                              hipStream_t stream){
  const float* q_in = (const float*)d_in[0];
  const float* k_in = (const float*)d_in[1];
  const float* v_in = (const float*)d_in[2];
  const float* Wq = (const float*)d_in[3];
  const float* bq = (const float*)d_in[4];
  const float* Wk = (const float*)d_in[5];
  const float* bk = (const float*)d_in[6];
  const float* Wv = (const float*)d_in[7];
  const float* bv = (const float*)d_in[8];
  const float* Wo = (const float*)d_in[9];
  const float* bo = (const float*)d_in[10];

  char* ws = (char*)d_ws;
  u16* Xb   = (u16*)ws;                                   // 3 x 4096x768 bf16
  u16* Wb   = (u16*)(ws + 18874368);                      // 4 x 768x768 bf16
  u16* QKVh = (u16*)(ws + 23592960);                      // Q,K head-split bf16; slot2 = V^T fp16
  u16* ctxb = (u16*)(ws + 42467328);                      // 4096x768 bf16

  cvt_kernel<<<dim3(3145728 / 1024, 3), 256, 0, stream>>>(
      q_in, k_in, v_in, nullptr, Xb, Xb + 3145728, Xb + 2 * 3145728, nullptr, 3145728);
  cvt_kernel<<<dim3(589824 / 1024, 4), 256, 0, stream>>>(
      Wq, Wk, Wv, Wo, Wb, Wb + 589824, Wb + 2 * 589824, Wb + 3 * 589824, 589824);

  gemm_bt<0><<<dim3(32, 6, 3), 256, 0, stream>>>(Xb, Wb, bq, bk, bv, QKVh, nullptr);

  attn6_kernel<<<dim3(SEQ / 16, NH, BATCH), 1024, 0, stream>>>(
      QKVh, QKVh + 3145728, QKVh + 2 * 3145728, ctxb);

  gemm_bt<1><<<dim3(32, 6, 1), 256, 0, stream>>>(
      ctxb, Wb + 3 * 589824, bo, bo, bo, nullptr, (float*)d_out);
}

// Round 7
// 305.524 us; speedup vs baseline: 3.9297x; 1.0261x over previous
//
#include <hip/hip_runtime.h>
#include <hip/hip_fp16.h>
#include <stdint.h>
#include <math.h>

#define NH    12
#define SEQ   2048
#define BATCH 2
#define DM    768
#define HD    64
#define SCALEF 0.125f      // 1/sqrt(64)

typedef unsigned short u16;
typedef unsigned int   u32;
typedef unsigned long long u64;
typedef __attribute__((ext_vector_type(8))) short bf16x8;
typedef __attribute__((ext_vector_type(8))) _Float16 h16x8;
typedef __attribute__((ext_vector_type(4))) float f32x4;

__device__ __forceinline__ u16 f2bf(float f){
  u32 u = __float_as_uint(f);
  u32 r = u + 0x7fffu + ((u >> 16) & 1u);
  return (u16)(r >> 16);
}
__device__ __forceinline__ float bf2f(u16 x){ return __uint_as_float(((u32)x) << 16); }
__device__ __forceinline__ u16 f2h(float f){ return __half_as_ushort(__float2half(f)); }
__device__ __forceinline__ float h2f(u16 x){ return __half2float(__ushort_as_half(x)); }

// order-preserving u16 key -> fp16 value
__device__ __forceinline__ float kval(u32 k){
  const u16 hb = (k & 0x8000u) ? (u16)(k & 0x7fffu) : (u16)(~k & 0xffffu);
  return h2f(hb);
}

// ---- DPP wave64 reductions (VALU pipe, no LDS) ----
__device__ __forceinline__ int dpp_sumi(int x){
  x += __builtin_amdgcn_update_dpp(0, x, 0x111, 0xf, 0xf, true);   // row_shr:1
  x += __builtin_amdgcn_update_dpp(0, x, 0x112, 0xf, 0xf, true);   // row_shr:2
  x += __builtin_amdgcn_update_dpp(0, x, 0x114, 0xf, 0xf, true);   // row_shr:4
  x += __builtin_amdgcn_update_dpp(0, x, 0x118, 0xf, 0xf, true);   // row_shr:8
  x += __builtin_amdgcn_update_dpp(0, x, 0x142, 0xa, 0xf, true);   // row_bcast:15
  x += __builtin_amdgcn_update_dpp(0, x, 0x143, 0xc, 0xf, true);   // row_bcast:31
  return __builtin_amdgcn_readlane(x, 63);
}
__device__ __forceinline__ int dpp_scan_incl(int x){
  x += __builtin_amdgcn_update_dpp(0, x, 0x111, 0xf, 0xf, true);
  x += __builtin_amdgcn_update_dpp(0, x, 0x112, 0xf, 0xf, true);
  x += __builtin_amdgcn_update_dpp(0, x, 0x114, 0xf, 0xf, true);
  x += __builtin_amdgcn_update_dpp(0, x, 0x118, 0xf, 0xf, true);
  x += __builtin_amdgcn_update_dpp(0, x, 0x142, 0xa, 0xf, true);
  x += __builtin_amdgcn_update_dpp(0, x, 0x143, 0xc, 0xf, true);
  return x;
}
__device__ __forceinline__ float dpp_sumf(float x){
  #define ASTEP(ctrl, rm) x += __int_as_float(__builtin_amdgcn_update_dpp(0, __float_as_int(x), ctrl, rm, 0xf, true));
  ASTEP(0x111,0xf) ASTEP(0x112,0xf) ASTEP(0x114,0xf) ASTEP(0x118,0xf) ASTEP(0x142,0xa) ASTEP(0x143,0xc)
  #undef ASTEP
  return __uint_as_float((u32)__builtin_amdgcn_readlane(__float_as_int(x), 63));
}
__device__ __forceinline__ float dpp_maxf(float x){
  #define MSTEP(ctrl, rm) { int o = __float_as_int(x); \
    x = fmaxf(x, __int_as_float(__builtin_amdgcn_update_dpp(o, o, ctrl, rm, 0xf, false))); }
  MSTEP(0x111,0xf) MSTEP(0x112,0xf) MSTEP(0x114,0xf) MSTEP(0x118,0xf) MSTEP(0x142,0xa) MSTEP(0x143,0xc)
  #undef MSTEP
  return __uint_as_float((u32)__builtin_amdgcn_readlane(__float_as_int(x), 63));
}
__device__ __forceinline__ int dpp_maxi(int x){
  #define ISTEP(ctrl, rm) { int o = x; int y = __builtin_amdgcn_update_dpp(o, o, ctrl, rm, 0xf, false); \
    x = (x > y) ? x : y; }
  ISTEP(0x111,0xf) ISTEP(0x112,0xf) ISTEP(0x114,0xf) ISTEP(0x118,0xf) ISTEP(0x142,0xa) ISTEP(0x143,0xc)
  #undef ISTEP
  return __builtin_amdgcn_readlane(x, 63);
}

// swizzled fp16 prob matrix P[16][2048] (u16 units)
__device__ __forceinline__ int pb_off(int q, int k){
  return (q << 11) + ((((k >> 3) ^ (q & 7)) << 3) | (k & 7));
}
// swizzled psum [4 kcopies][16 q][64 d] (f32 units)
__device__ __forceinline__ int ps_off(int kc, int q, int d){
  return (kc << 10) + (q << 6) + ((((d >> 2) ^ q) & 15) << 2) + (d & 3);
}

// ---------------------------------------------------------------- cvt fp32->bf16
__global__ void cvt_kernel(const float* s0, const float* s1, const float* s2, const float* s3,
                           u16* d0, u16* d1, u16* d2, u16* d3, int n){
  const float* s; u16* d;
  switch (blockIdx.y){
    case 0: s = s0; d = d0; break;
    case 1: s = s1; d = d1; break;
    case 2: s = s2; d = d2; break;
    default: s = s3; d = d3; break;
  }
  int i = (blockIdx.x * 256 + threadIdx.x) * 4;
  if (i < n){
    float4 v = *(const float4*)(s + i);
    ushort4 o;
    o.x = f2bf(v.x); o.y = f2bf(v.y); o.z = f2bf(v.z); o.w = f2bf(v.w);
    *(ushort4*)(d + i) = o;
  }
}

// ---------------------------------------------------------------- GEMM  C = A @ W^T (+bias)
// MODE 0: zz=0,1 -> bf16 head-split [(b*NH+h)*SEQ+s]*HD+d ; zz=2 -> fp16 V^T [(b*NH+h)*HD+d]*SEQ+s
// MODE 1: out fp32 plain [m][n]
template<int MODE>
__global__ __launch_bounds__(256) void gemm_bt(const u16* __restrict__ Aall, const u16* __restrict__ Wall,
      const float* __restrict__ bz0, const float* __restrict__ bz1, const float* __restrict__ bz2,
      u16* __restrict__ outb, float* __restrict__ outf){
  __shared__ u16 As[128][40];
  __shared__ u16 Bs[128][40];
  const int zz = blockIdx.z;
  const u16* A = Aall + (size_t)zz * 4096 * 768;
  const u16* W = Wall + (size_t)zz * 768 * 768;
  const float* bias = (zz == 0) ? bz0 : (zz == 1 ? bz1 : bz2);
  const int m0 = blockIdx.x * 128, n0 = blockIdx.y * 128;
  const int t = threadIdx.x, lane = t & 63, wv = t >> 6;
  const int wm = wv >> 1, wn = wv & 1;
  f32x4 acc[4][4] = {};
  const int arow = t >> 1, aseg = t & 1;
  const u16* ap = A + (size_t)(m0 + arow) * 768 + aseg * 16;
  const u16* bp = W + (size_t)(n0 + arow) * 768 + aseg * 16;
  for (int kt = 0; kt < 768; kt += 32){
    uint4 av0 = *(const uint4*)(ap + kt);
    uint4 av1 = *(const uint4*)(ap + kt + 8);
    uint4 bv0 = *(const uint4*)(bp + kt);
    uint4 bv1 = *(const uint4*)(bp + kt + 8);
    __syncthreads();
    *(uint4*)&As[arow][aseg*16]     = av0;
    *(uint4*)&As[arow][aseg*16 + 8] = av1;
    *(uint4*)&Bs[arow][aseg*16]     = bv0;
    *(uint4*)&Bs[arow][aseg*16 + 8] = bv1;
    __syncthreads();
    bf16x8 af[4], bq[4];
    #pragma unroll
    for (int i = 0; i < 4; ++i) af[i] = *(const bf16x8*)&As[wm*64 + i*16 + (lane & 15)][(lane >> 4) * 8];
    #pragma unroll
    for (int i = 0; i < 4; ++i) bq[i] = *(const bf16x8*)&Bs[wn*64 + i*16 + (lane & 15)][(lane >> 4) * 8];
    #pragma unroll
    for (int mi = 0; mi < 4; ++mi)
      #pragma unroll
      for (int ni = 0; ni < 4; ++ni)
        acc[mi][ni] = __builtin_amdgcn_mfma_f32_16x16x32_bf16(af[mi], bq[ni], acc[mi][ni], 0, 0, 0);
  }
  #pragma unroll
  for (int mi = 0; mi < 4; ++mi){
    #pragma unroll
    for (int ni = 0; ni < 4; ++ni){
      const int n = n0 + wn*64 + ni*16 + (lane & 15);
      const float bval = bias[n];
      const int mbase = m0 + wm*64 + mi*16 + (lane >> 4) * 4;
      if (MODE == 0 && zz == 2){
        const int bb = mbase >> 11, ss = mbase & 2047;
        const int hh = n >> 6, dd = n & 63;
        u64 pk = 0;
        #pragma unroll
        for (int r = 0; r < 4; ++r) pk |= (u64)f2h(acc[mi][ni][r] + bval) << (16 * r);
        *(u64*)(outb + (size_t)2 * 3145728 + (((size_t)(bb * NH + hh) * HD + dd) * SEQ + ss)) = pk;
      } else if (MODE == 0){
        #pragma unroll
        for (int r = 0; r < 4; ++r){
          const int m = mbase + r;
          const int bb = m >> 11, ss = m & 2047, hh = n >> 6, dd = n & 63;
          outb[(size_t)zz * 3145728 + (((size_t)bb * NH + hh) * SEQ + ss) * HD + dd] = f2bf(acc[mi][ni][r] + bval);
        }
      } else {
        #pragma unroll
        for (int r = 0; r < 4; ++r){
          const int m = mbase + r;
          outf[(size_t)m * DM + n] = acc[mi][ni][r] + bval;
        }
      }
    }
  }
}

// ---------------------------------------------------------------- fused attention v7
// grid (SEQ/16, NH, BATCH), 1024 threads (16 waves), 1 query per wave.
// Selection: bracket-probe + candidate compaction (<=256) + exact bisect on 4 regs/lane.
// No LDS atomics, no svals/sidx arrays; sparse softmax from candidate registers.
__global__ __launch_bounds__(1024, 8) void attn7_kernel(const u16* __restrict__ Qh,
      const u16* __restrict__ Kh, const u16* __restrict__ Vt, u16* __restrict__ ctxb){
  __shared__ __align__(16) u32 smem[20480];    // 81,920 B
  u16*  Pm    = (u16*)smem;                    // [16][2048] fp16 (overlays score stripe)
  float* psum = (float*)(smem + 16384);        // [4][16][64] f32 (phase D/E, overlays cand)

  const int q0 = blockIdx.x * 16;
  const int h = blockIdx.y, b = blockIdx.z, bh = b * NH + h;
  const int t = threadIdx.x, lane = t & 63, w = t >> 6;
  const u16* Qb  = Qh + ((size_t)bh * SEQ + q0) * HD;
  const u16* Kb  = Kh + (size_t)bh * SEQ * HD;
  const u16* Vtb = Vt + (size_t)bh * HD * SEQ;

  // ---- phase A: QK^T -> fp16 scores. wave w covers keys [w*128, w*128+128), all 16 queries.
  {
    const int qcol = lane & 15;
    const bf16x8 qa0 = *(const bf16x8*)(Qb + qcol * HD + (lane >> 4) * 8);
    const bf16x8 qa1 = *(const bf16x8*)(Qb + qcol * HD + 32 + (lane >> 4) * 8);
    #pragma unroll 4
    for (int tile = 0; tile < 8; ++tile){
      const int kr = w * 128 + tile * 16 + (lane & 15);
      const bf16x8 ka0 = *(const bf16x8*)(Kb + (size_t)kr * HD + (lane >> 4) * 8);
      const bf16x8 ka1 = *(const bf16x8*)(Kb + (size_t)kr * HD + 32 + (lane >> 4) * 8);
      f32x4 d = {};
      d = __builtin_amdgcn_mfma_f32_16x16x32_bf16(ka0, qa0, d, 0, 0, 0);
      d = __builtin_amdgcn_mfma_f32_16x16x32_bf16(ka1, qa1, d, 0, 0, 0);
      const int kbase = w * 128 + tile * 16 + (lane >> 4) * 4;
      const u32 lo = (u32)f2h(d[0] * SCALEF) | ((u32)f2h(d[1] * SCALEF) << 16);
      const u32 hi = (u32)f2h(d[2] * SCALEF) | ((u32)f2h(d[3] * SCALEF) << 16);
      const int off = (qcol << 10) | ((kbase >> 1) ^ (qcol << 1));
      *(u64*)(smem + off) = (u64)lo | ((u64)hi << 32);
    }
  }
  __syncthreads();

  // ---- phase B: wave w loads its query row (q = w) as PACKED order-preserving u16 keys
  const int qi = q0 + w;
  const int sw = w << 1;
  u32* rowp = smem + (w << 10);
  u32* cand = smem + 16384 + (w << 8);   // wave-private 256 dwords
  u32 ukp[16];
  #pragma unroll
  for (int i = 0; i < 16; ++i){
    const u32 dw = rowp[(lane + 64 * i) ^ sw];
    const u32 s = (dw >> 15) & 0x00010001u;
    ukp[i] = dw ^ (0x80008000u | (s * 0x7fffu));   // per-half: neg -> ~x, pos -> x|0x8000
  }
  __asm__ volatile("" ::: "memory");

  // ---- wave max key M
  u32 pmx = ukp[0];
  #pragma unroll
  for (int i = 1; i < 16; ++i){
    const u32 a = ukp[i];
    const u32 l = (a & 0xffffu) > (pmx & 0xffffu) ? (a & 0xffffu) : (pmx & 0xffffu);
    const u32 hh = (a >> 16) > (pmx >> 16) ? (a >> 16) : (pmx >> 16);
    pmx = l | (hh << 16);
  }
  u32 Mk = (pmx & 0xffffu) > (pmx >> 16) ? (pmx & 0xffffu) : (pmx >> 16);
  Mk = (u32)dpp_maxi((int)Mk);
  const float m1 = kval(Mk);

  // ---- bracket search: find lo with count(>=lo) in [64,240] (seed = M - 1 quarter-octave*4)
  u32 blo = 0;  int c_lo = 2048;
  u32 bhi = Mk + 1; int c_hi = 0;
  {
    u32 tm = (Mk > 1024u) ? (Mk - 1024u) : 1u;
    if (tm >= bhi) tm = (blo + bhi) >> 1;
    #pragma unroll 1
    for (int it = 0; it < 12; ++it){
      int cl = 0;
      #pragma unroll
      for (int i = 0; i < 16; ++i){
        cl += ((ukp[i] & 0xffffu) >= tm) ? 1 : 0;
        cl += ((ukp[i] >> 16) >= tm) ? 1 : 0;
      }
      const int c = dpp_sumi(cl);
      if (c >= 64){ blo = tm; c_lo = c; if (c <= 240) break; }
      else        { bhi = tm; c_hi = c; }
      const u32 nt = (blo + bhi) >> 1;
      if (nt == blo) break;
      tm = nt;
    }
  }

  // ---- compact candidates (key >= blo) to LDS as (key<<16)|(2047-idx)
  int n_c;
  {
    int cl = 0;
    #pragma unroll
    for (int i = 0; i < 16; ++i){
      cl += ((ukp[i] & 0xffffu) >= blo) ? 1 : 0;
      cl += ((ukp[i] >> 16) >= blo) ? 1 : 0;
    }
    const int incl = dpp_scan_incl(cl);
    const int totalc = __builtin_amdgcn_readlane(incl, 63);
    int pos = incl - cl;
    #pragma unroll
    for (int i = 0; i < 16; ++i){
      #pragma unroll
      for (int hh = 0; hh < 2; ++hh){
        const u32 kk = hh ? (ukp[i] >> 16) : (ukp[i] & 0xffffu);
        if (kk >= blo && pos < 256){
          const int idx = 2 * lane + (i << 7) + hh;
          cand[pos] = (kk << 16) | (u32)(2047 - idx);
          ++pos;
        }
      }
    }
    n_c = totalc < 256 ? totalc : 256;
  }
  __asm__ volatile("s_waitcnt lgkmcnt(0)" ::: "memory");

  // ---- load 4 candidates/lane, exact bisect for T on candidates
  u32 cj[4];
  #pragma unroll
  for (int j = 0; j < 4; ++j){
    const int s = lane + 64 * j;
    const u32 vv = cand[s];
    cj[j] = (s < n_c) ? vv : 0u;
  }
  while (bhi - blo > 1u){
    const u32 tm = (blo + bhi) >> 1;
    const u32 kthr = tm << 16;
    int cl = 0;
    #pragma unroll
    for (int j = 0; j < 4; ++j) cl += (cj[j] >= kthr) ? 1 : 0;
    const int c = dpp_sumi(cl);
    if (c >= 64){ blo = tm; c_lo = c; } else { bhi = tm; c_hi = c; }
  }
  const u32 T = blo;          // exact 64th-largest fp16 key
  const int G = c_hi;         // count(> T)
  const int r_need = 64 - G;  // ties to take

  // ---- sparse softmax pieces from registers
  float ev[4]; int eqc = 0;
  float zl = 0.f;
  #pragma unroll
  for (int j = 0; j < 4; ++j){
    const u32 key = cj[j] >> 16;
    ev[j] = __expf(kval(key) - m1);
    zl += (key > T) ? ev[j] : 0.f;
    eqc += (key == T) ? 1 : 0;
  }
  const int pre_eq = dpp_scan_incl(eqc) - eqc;
  const float eT = __expf(kval(T) - m1);
  const float Z1 = dpp_sumf(zl) + (float)r_need * eT;
  const float inv1 = 0.5f / Z1;

  // ---- windowed causal branch: read window scores (row still intact)
  const int start = (qi - 256 > 0) ? (qi - 256) : 0;
  float wvv[5];
  #pragma unroll
  for (int it = 0; it < 5; ++it){
    const int c0 = start + lane + it * 64;
    const int c = (c0 <= qi) ? c0 : qi;
    const u32 dw = rowp[(c >> 1) ^ sw];
    const u16 hb = (c & 1) ? (u16)(dw >> 16) : (u16)(dw & 0xffffu);
    wvv[it] = (c0 <= qi) ? h2f(hb) : -INFINITY;
  }
  float wm = -INFINITY;
  #pragma unroll
  for (int it = 0; it < 5; ++it) wm = fmaxf(wm, wvv[it]);
  wm = dpp_maxf(wm);
  float zs = 0.f;
  #pragma unroll
  for (int it = 0; it < 5; ++it){
    const int c = start + lane + it * 64;
    if (c <= qi){ const float e = __expf(wvv[it] - wm); wvv[it] = e; zs += e; }
  }
  zs = dpp_sumf(zs);
  const float inv = 0.5f / zs;

  // ---- build P row w in place: zero, window scatter, sparse scatter-add
  {
    uint4* prow = (uint4*)(Pm + (w << 11));
    const uint4 z4 = {0u, 0u, 0u, 0u};
    #pragma unroll
    for (int i = 0; i < 4; ++i) prow[lane + i * 64] = z4;
    __asm__ volatile("" ::: "memory");
    #pragma unroll
    for (int it = 0; it < 5; ++it){
      const int c = start + lane + it * 64;
      if (c <= qi) Pm[pb_off(w, c)] = f2h(wvv[it] * inv);
    }
    __asm__ volatile("" ::: "memory");
    int rloc = pre_eq;
    #pragma unroll
    for (int j = 0; j < 4; ++j){
      const u32 key = cj[j] >> 16;
      const bool isgt = key > T;
      const bool iseq = (key == T);
      const bool sel = isgt || (iseq && rloc < r_need);
      if (iseq) ++rloc;
      if (sel){
        const int idx = 2047 - (int)(cj[j] & 0x7ffu);
        u16* cell = &Pm[pb_off(w, idx)];
        *cell = f2h(h2f(*cell) + ev[j] * inv1);
      }
    }
  }
  __syncthreads();

  // ---- phase D: PV via fp16 MFMA. out^T[d][q] = V^T · P^T. 4-way K-split.
  {
    const int kc = w >> 2, mi = w & 3;
    f32x4 acc = {};
    #pragma unroll 4
    for (int ks = 0; ks < 16; ++ks){
      const int kk = kc * 512 + ks * 32;
      const h16x8 va = *(const h16x8*)(Vtb + (size_t)(mi * 16 + (lane & 15)) * SEQ + kk + (lane >> 4) * 8);
      const h16x8 pf = *(const h16x8*)&Pm[pb_off(lane & 15, kk + (lane >> 4) * 8)];
      acc = __builtin_amdgcn_mfma_f32_16x16x32_f16(va, pf, acc, 0, 0, 0);
    }
    const int q = lane & 15, dbase = mi * 16 + (lane >> 4) * 4;
    *(f32x4*)&psum[ps_off(kc, q, dbase)] = acc;
  }
  __syncthreads();

  // ---- phase E: reduce 4 K-copies, write bf16 ctx
  {
    const int q = t >> 6, d = t & 63;
    const float r = psum[ps_off(0, q, d)] + psum[ps_off(1, q, d)]
                  + psum[ps_off(2, q, d)] + psum[ps_off(3, q, d)];
    ctxb[((size_t)(b * SEQ + q0 + q)) * DM + h * HD + d] = f2bf(r);
  }
}

// ---------------------------------------------------------------- host
extern "C" void kernel_launch(void* const* d_in, const int* in_sizes, int n_in,
                              void* d_out, int out_size, void* d_ws, size_t ws_size,
                              hipStream_t stream){
  const float* q_in = (const float*)d_in[0];
  const float* k_in = (const float*)d_in[1];
  const float* v_in = (const float*)d_in[2];
  const float* Wq = (const float*)d_in[3];
  const float* bq = (const float*)d_in[4];
  const float* Wk = (const float*)d_in[5];
  const float* bk = (const float*)d_in[6];
  const float* Wv = (const float*)d_in[7];
  const float* bv = (const float*)d_in[8];
  const float* Wo = (const float*)d_in[9];
  const float* bo = (const float*)d_in[10];

  char* ws = (char*)d_ws;
  u16* Xb   = (u16*)ws;                                   // 3 x 4096x768 bf16
  u16* Wb   = (u16*)(ws + 18874368);                      // 4 x 768x768 bf16
  u16* QKVh = (u16*)(ws + 23592960);                      // Q,K head-split bf16; slot2 = V^T fp16
  u16* ctxb = (u16*)(ws + 42467328);                      // 4096x768 bf16

  cvt_kernel<<<dim3(3145728 / 1024, 3), 256, 0, stream>>>(
      q_in, k_in, v_in, nullptr, Xb, Xb + 3145728, Xb + 2 * 3145728, nullptr, 3145728);
  cvt_kernel<<<dim3(589824 / 1024, 4), 256, 0, stream>>>(
      Wq, Wk, Wv, Wo, Wb, Wb + 589824, Wb + 2 * 589824, Wb + 3 * 589824, 589824);

  gemm_bt<0><<<dim3(32, 6, 3), 256, 0, stream>>>(Xb, Wb, bq, bk, bv, QKVh, nullptr);

  attn7_kernel<<<dim3(SEQ / 16, NH, BATCH), 1024, 0, stream>>>(
      QKVh, QKVh + 3145728, QKVh + 2 * 3145728, ctxb);

  gemm_bt<1><<<dim3(32, 6, 1), 256, 0, stream>>>(
      ctxb, Wb + 3 * 589824, bo, bo, bo, nullptr, (float*)d_out);
}